// Round 1
// baseline (1539.045 us; speedup 1.0000x reference)
//
#include <hip/hip_runtime.h>

// RGCN node classification: 3 layers of per-relation mean aggregation.
// Strategy: build CSR (dst-sorted edges) once per call, pull-aggregate (no atomics),
// matmul-first for weighted layers (agg_r(h@W) == agg_r(h)@W).

enum { F_ACC = 1, F_RELU = 2, F_BIAS = 4 };

__global__ void deg_count_k(const int* __restrict__ dst, int RE, int E, int Nn,
                            int* __restrict__ degcnt) {
  int g = blockIdx.x * blockDim.x + threadIdx.x;
  if (g < RE) {
    int r = g / E;
    atomicAdd(&degcnt[(size_t)r * Nn + dst[g]], 1);
  }
}

// One block (1024 threads) per relation: exclusive scan of degcnt -> rowptr,
// init cursor, compute invdeg = 1/max(deg,1).
__global__ __launch_bounds__(1024) void scan_k(const int* __restrict__ degcnt, int Nn,
                                               int* __restrict__ rowptr,
                                               int* __restrict__ cursor,
                                               float* __restrict__ invdeg) {
  __shared__ int part[1024];
  int r = blockIdx.x;
  const int* d = degcnt + (size_t)r * Nn;
  int chunk = (Nn + 1023) >> 10;
  int t = threadIdx.x;
  int begin = t * chunk;
  int end = begin + chunk; if (end > Nn) end = Nn;
  int s = 0;
  for (int i = begin; i < end; i++) s += d[i];
  part[t] = s;
  __syncthreads();
  for (int off = 1; off < 1024; off <<= 1) {
    int v = (t >= off) ? part[t - off] : 0;
    __syncthreads();
    part[t] += v;
    __syncthreads();
  }
  int run = (t == 0) ? 0 : part[t - 1];
  int* rp = rowptr + (size_t)r * (Nn + 1);
  for (int i = begin; i < end; i++) {
    int dd = d[i];
    rp[i] = run;
    cursor[(size_t)r * Nn + i] = run;
    invdeg[(size_t)r * Nn + i] = 1.0f / (float)(dd > 0 ? dd : 1);
    run += dd;
  }
  if (t == 1023) rp[Nn] = part[1023];
}

__global__ void fill_k(const int* __restrict__ src, const int* __restrict__ dst,
                       int RE, int E, int Nn,
                       int* __restrict__ cursor, int* __restrict__ eidx) {
  int g = blockIdx.x * blockDim.x + threadIdx.x;
  if (g < RE) {
    int r = g / E;
    int pos = atomicAdd(&cursor[(size_t)r * Nn + dst[g]], 1);
    eidx[(size_t)r * E + pos] = src[g];
  }
}

// Pull aggregation, D=256: one wave per node, lane holds float4 (cols lane*4..lane*4+3).
__global__ __launch_bounds__(256) void pull256_k(
    const float* __restrict__ x, long xrstride,
    const int* __restrict__ eidx, int E,
    const int* __restrict__ rowptr, const float* __restrict__ invdeg,
    int nrel, int rel0, int Nn,
    float* __restrict__ acc, const float* __restrict__ bias, int flags) {
  int wid = (blockIdx.x * blockDim.x + threadIdx.x) >> 6;
  if (wid >= Nn) return;
  int lane = threadIdx.x & 63;
  float sx = 0.f, sy = 0.f, sz = 0.f, sw = 0.f;
  for (int rr = 0; rr < nrel; rr++) {
    int r = rel0 + rr;
    const int* rp = rowptr + (size_t)r * (Nn + 1);
    int s = rp[wid], e = rp[wid + 1];
    const int* ei = eidx + (size_t)r * E;
    const float* xr = x + (size_t)rr * xrstride;
    float px = 0.f, py = 0.f, pz = 0.f, pw = 0.f;
    for (int i = s; i < e; i++) {
      int sn = ei[i];
      const float4 v = *reinterpret_cast<const float4*>(xr + ((size_t)sn << 8) + (lane << 2));
      px += v.x; py += v.y; pz += v.z; pw += v.w;
    }
    float w = invdeg[(size_t)r * Nn + wid];
    sx += px * w; sy += py * w; sz += pz * w; sw += pw * w;
  }
  size_t o = ((size_t)wid << 8) + (lane << 2);
  if (flags & F_ACC) {
    const float4 p = *reinterpret_cast<const float4*>(acc + o);
    sx += p.x; sy += p.y; sz += p.z; sw += p.w;
  }
  if (flags & F_BIAS) {
    const float4 b = *reinterpret_cast<const float4*>(bias + (lane << 2));
    sx += b.x; sy += b.y; sz += b.z; sw += b.w;
  }
  if (flags & F_RELU) {
    sx = fmaxf(sx, 0.f); sy = fmaxf(sy, 0.f); sz = fmaxf(sz, 0.f); sw = fmaxf(sw, 0.f);
  }
  float4 ov; ov.x = sx; ov.y = sy; ov.z = sz; ov.w = sw;
  *reinterpret_cast<float4*>(acc + o) = ov;
}

// Pull aggregation, D=64: one wave per node, lane holds one float.
__global__ __launch_bounds__(256) void pull64_k(
    const float* __restrict__ x,
    const int* __restrict__ eidx, int E,
    const int* __restrict__ rowptr, const float* __restrict__ invdeg,
    int rel, int Nn,
    float* __restrict__ acc, const float* __restrict__ bias, int flags) {
  int wid = (blockIdx.x * blockDim.x + threadIdx.x) >> 6;
  if (wid >= Nn) return;
  int lane = threadIdx.x & 63;
  const int* rp = rowptr + (size_t)rel * (Nn + 1);
  int s = rp[wid], e = rp[wid + 1];
  const int* ei = eidx + (size_t)rel * E;
  float sum = 0.f;
  for (int i = s; i < e; i++) sum += x[((size_t)ei[i] << 6) + lane];
  sum *= invdeg[(size_t)rel * Nn + wid];
  float o = sum;
  size_t oo = ((size_t)wid << 6) + lane;
  if (flags & F_ACC) o += acc[oo];
  if (flags & F_BIAS) o += bias[lane];
  if (flags & F_RELU) o = fmaxf(o, 0.f);
  acc[oo] = o;
}

// Simple tiled f32 GEMM: C[M,Nd] = A[M,K] @ B[K,Nd]. 64x64 tile, 256 threads, 4x4/thread.
__global__ __launch_bounds__(256) void gemm_f32_k(const float* __restrict__ A,
                                                  const float* __restrict__ B,
                                                  float* __restrict__ Cc,
                                                  int M, int K, int Nd) {
  __shared__ float As[64][17];
  __shared__ float Bs[16][64];
  int tid = threadIdx.x;
  int tx = tid & 15;
  int ty = tid >> 4;
  int rowBase = blockIdx.y * 64;
  int colBase = blockIdx.x * 64;
  float c[4][4] = {};
  for (int k0 = 0; k0 < K; k0 += 16) {
    {
      int rr = tid >> 2;
      int kk = (tid & 3) * 4;
      int gr = rowBase + rr;
      float4 v = {0.f, 0.f, 0.f, 0.f};
      if (gr < M) v = *reinterpret_cast<const float4*>(A + (size_t)gr * K + k0 + kk);
      As[rr][kk] = v.x; As[rr][kk + 1] = v.y; As[rr][kk + 2] = v.z; As[rr][kk + 3] = v.w;
    }
    {
      int kr = tid >> 4;
      int cc = (tid & 15) * 4;
      float4 v = *reinterpret_cast<const float4*>(B + (size_t)(k0 + kr) * Nd + colBase + cc);
      *reinterpret_cast<float4*>(&Bs[kr][cc]) = v;
    }
    __syncthreads();
#pragma unroll
    for (int k = 0; k < 16; k++) {
      float a[4], b[4];
#pragma unroll
      for (int i = 0; i < 4; i++) a[i] = As[ty * 4 + i][k];
#pragma unroll
      for (int j = 0; j < 4; j++) b[j] = Bs[k][tx * 4 + j];
#pragma unroll
      for (int i = 0; i < 4; i++)
#pragma unroll
        for (int j = 0; j < 4; j++) c[i][j] += a[i] * b[j];
    }
    __syncthreads();
  }
  for (int i = 0; i < 4; i++) {
    int gr = rowBase + ty * 4 + i;
    if (gr < M) {
      float4 v; v.x = c[i][0]; v.y = c[i][1]; v.z = c[i][2]; v.w = c[i][3];
      *reinterpret_cast<float4*>(Cc + (size_t)gr * Nd + colBase + tx * 4) = v;
    }
  }
}

extern "C" void kernel_launch(void* const* d_in, const int* in_sizes, int n_in,
                              void* d_out, int out_size, void* d_ws, size_t ws_size,
                              hipStream_t stream) {
  const float* embed = (const float*)d_in[0];
  const int* src     = (const int*)d_in[1];
  const int* dst     = (const int*)d_in[2];
  const float* b0    = (const float*)d_in[3];
  const float* w1    = (const float*)d_in[4];
  const float* b1    = (const float*)d_in[5];
  const float* w_out = (const float*)d_in[6];
  const float* b_out = (const float*)d_in[7];
  float* out = (float*)d_out;

  const int D = in_sizes[3];            // 256
  const int C = in_sizes[7];            // 64
  const int N = in_sizes[0] / D;        // 50000
  const int R = in_sizes[4] / (D * D);  // 4
  const int E = in_sizes[1] / R;        // 400000
  const int RE = R * E;

  char* w = (char*)d_ws;
  size_t off = 0;
  auto carve = [&](size_t bytes) -> void* {
    void* p = w + off;
    off += (bytes + 255) & ~(size_t)255;
    return p;
  };
  float* h      = (float*)carve((size_t)N * D * 4);
  float* h2     = (float*)carve((size_t)N * D * 4);
  float* t      = (float*)carve((size_t)N * D * 4);
  float* invdeg = (float*)carve((size_t)R * N * 4);
  int* degcnt   = (int*)carve((size_t)R * N * 4);
  int* rowptr   = (int*)carve((size_t)R * (N + 1) * 4);
  int* cursor   = (int*)carve((size_t)R * N * 4);
  int* eidx     = (int*)carve((size_t)RE * 4);
  (void)ws_size; (void)n_in; (void)out_size;

  // --- build CSR (per call; graph shared by all 3 layers) ---
  hipMemsetAsync(degcnt, 0, (size_t)R * N * 4, stream);
  deg_count_k<<<(RE + 255) / 256, 256, 0, stream>>>(dst, RE, E, N, degcnt);
  scan_k<<<R, 1024, 0, stream>>>(degcnt, N, rowptr, cursor, invdeg);
  fill_k<<<(RE + 255) / 256, 256, 0, stream>>>(src, dst, RE, E, N, cursor, eidx);

  int pullBlocks = (N * 64 + 255) / 256;

  // --- layer 0: h = relu(b0 + sum_r agg_r(embed)) ---
  pull256_k<<<pullBlocks, 256, 0, stream>>>(embed, 0, eidx, E, rowptr, invdeg,
                                            R, 0, N, h, b0, F_BIAS | F_RELU);

  // --- layer 1: h2 = relu(b1 + sum_r agg_r(h @ w1[r])) ---
  for (int r = 0; r < R; r++) {
    dim3 g(D / 64, (N + 63) / 64);
    gemm_f32_k<<<g, 256, 0, stream>>>(h, w1 + (size_t)r * D * D, t, N, D, D);
    int fl = (r ? F_ACC : 0) | (r == R - 1 ? (F_BIAS | F_RELU) : 0);
    pull256_k<<<pullBlocks, 256, 0, stream>>>(t, 0, eidx, E, rowptr, invdeg,
                                              1, r, N, h2, b1, fl);
  }

  // --- layer 2: out = b_out + sum_r agg_r(h2 @ w_out[r]) ---
  for (int r = 0; r < R; r++) {
    dim3 g(C / 64, (N + 63) / 64);
    gemm_f32_k<<<g, 256, 0, stream>>>(h2, w_out + (size_t)r * D * C, t, N, D, C);
    int fl = (r ? F_ACC : F_BIAS);
    pull64_k<<<pullBlocks, 256, 0, stream>>>(t, eidx, E, rowptr, invdeg, r, N, out, b_out, fl);
  }
}

// Round 2
// 1379.681 us; speedup vs baseline: 1.1155x; 1.1155x over previous
//
#include <hip/hip_runtime.h>

// RGCN node classification: 3 layers of per-relation mean aggregation.
// CSR build once per call; pull-aggregation (no atomics); matmul-first
// (agg_r(h@W) == agg_r(h)@W); relations fused into batched GEMM + one
// multi-relation pull per layer (in-register cross-relation accumulation).

enum { F_ACC = 1, F_RELU = 2, F_BIAS = 4 };

__global__ void deg_count_k(const int* __restrict__ dst, int RE, int E, int Nn,
                            int* __restrict__ degcnt) {
  int g = blockIdx.x * blockDim.x + threadIdx.x;
  if (g < RE) {
    int r = g / E;
    atomicAdd(&degcnt[(size_t)r * Nn + dst[g]], 1);
  }
}

// One block (1024 threads) per relation: exclusive scan of degcnt -> rowptr,
// init cursor, compute invdeg = 1/max(deg,1).
__global__ __launch_bounds__(1024) void scan_k(const int* __restrict__ degcnt, int Nn,
                                               int* __restrict__ rowptr,
                                               int* __restrict__ cursor,
                                               float* __restrict__ invdeg) {
  __shared__ int part[1024];
  int r = blockIdx.x;
  const int* d = degcnt + (size_t)r * Nn;
  int chunk = (Nn + 1023) >> 10;
  int t = threadIdx.x;
  int begin = t * chunk;
  int end = begin + chunk; if (end > Nn) end = Nn;
  int s = 0;
  for (int i = begin; i < end; i++) s += d[i];
  part[t] = s;
  __syncthreads();
  for (int off = 1; off < 1024; off <<= 1) {
    int v = (t >= off) ? part[t - off] : 0;
    __syncthreads();
    part[t] += v;
    __syncthreads();
  }
  int run = (t == 0) ? 0 : part[t - 1];
  int* rp = rowptr + (size_t)r * (Nn + 1);
  for (int i = begin; i < end; i++) {
    int dd = d[i];
    rp[i] = run;
    cursor[(size_t)r * Nn + i] = run;
    invdeg[(size_t)r * Nn + i] = 1.0f / (float)(dd > 0 ? dd : 1);
    run += dd;
  }
  if (t == 1023) rp[Nn] = part[1023];
}

__global__ void fill_k(const int* __restrict__ src, const int* __restrict__ dst,
                       int RE, int E, int Nn,
                       int* __restrict__ cursor, int* __restrict__ eidx) {
  int g = blockIdx.x * blockDim.x + threadIdx.x;
  if (g < RE) {
    int r = g / E;
    int pos = atomicAdd(&cursor[(size_t)r * Nn + dst[g]], 1);
    eidx[(size_t)r * E + pos] = src[g];
  }
}

// Pull aggregation, D=256: one wave per node, lane holds float4.
// Unroll-4 gather: 4 eidx loads then 4 independent 1KB row gathers in flight.
__global__ __launch_bounds__(256) void pull256_k(
    const float* __restrict__ x, long xrstride, int D,
    const int* __restrict__ eidx, int E,
    const int* __restrict__ rowptr, const float* __restrict__ invdeg,
    int nrel, int rel0, int Nn,
    float* __restrict__ acc, const float* __restrict__ bias, int flags) {
  int wid = (blockIdx.x * blockDim.x + threadIdx.x) >> 6;
  if (wid >= Nn) return;
  int lane = threadIdx.x & 63;
  int col4 = lane << 2;
  float sx = 0.f, sy = 0.f, sz = 0.f, sw = 0.f;
  for (int rr = 0; rr < nrel; rr++) {
    int r = rel0 + rr;
    const int* rp = rowptr + (size_t)r * (Nn + 1);
    int s = rp[wid], e = rp[wid + 1];
    const int* ei = eidx + (size_t)r * E;
    const float* xr = x + (size_t)rr * xrstride;
    float px = 0.f, py = 0.f, pz = 0.f, pw = 0.f;
    int i = s;
    int e4 = s + ((e - s) & ~3);
    for (; i < e4; i += 4) {
      int n0 = ei[i + 0], n1 = ei[i + 1], n2 = ei[i + 2], n3 = ei[i + 3];
      const float4 v0 = *reinterpret_cast<const float4*>(xr + (size_t)n0 * D + col4);
      const float4 v1 = *reinterpret_cast<const float4*>(xr + (size_t)n1 * D + col4);
      const float4 v2 = *reinterpret_cast<const float4*>(xr + (size_t)n2 * D + col4);
      const float4 v3 = *reinterpret_cast<const float4*>(xr + (size_t)n3 * D + col4);
      px += (v0.x + v1.x) + (v2.x + v3.x);
      py += (v0.y + v1.y) + (v2.y + v3.y);
      pz += (v0.z + v1.z) + (v2.z + v3.z);
      pw += (v0.w + v1.w) + (v2.w + v3.w);
    }
    for (; i < e; i++) {
      int sn = ei[i];
      const float4 v = *reinterpret_cast<const float4*>(xr + (size_t)sn * D + col4);
      px += v.x; py += v.y; pz += v.z; pw += v.w;
    }
    float w = invdeg[(size_t)r * Nn + wid];
    sx += px * w; sy += py * w; sz += pz * w; sw += pw * w;
  }
  size_t o = (size_t)wid * D + col4;
  if (flags & F_ACC) {
    const float4 p = *reinterpret_cast<const float4*>(acc + o);
    sx += p.x; sy += p.y; sz += p.z; sw += p.w;
  }
  if (flags & F_BIAS) {
    const float4 b = *reinterpret_cast<const float4*>(bias + col4);
    sx += b.x; sy += b.y; sz += b.z; sw += b.w;
  }
  if (flags & F_RELU) {
    sx = fmaxf(sx, 0.f); sy = fmaxf(sy, 0.f); sz = fmaxf(sz, 0.f); sw = fmaxf(sw, 0.f);
  }
  float4 ov; ov.x = sx; ov.y = sy; ov.z = sz; ov.w = sw;
  *reinterpret_cast<float4*>(acc + o) = ov;
}

// Pull aggregation, D=64: one wave per node, lane holds one float. Unroll-8.
__global__ __launch_bounds__(256) void pull64_k(
    const float* __restrict__ x, long xrstride, int D,
    const int* __restrict__ eidx, int E,
    const int* __restrict__ rowptr, const float* __restrict__ invdeg,
    int nrel, int rel0, int Nn,
    float* __restrict__ acc, const float* __restrict__ bias, int flags) {
  int wid = (blockIdx.x * blockDim.x + threadIdx.x) >> 6;
  if (wid >= Nn) return;
  int lane = threadIdx.x & 63;
  float sum = 0.f;
  for (int rr = 0; rr < nrel; rr++) {
    int r = rel0 + rr;
    const int* rp = rowptr + (size_t)r * (Nn + 1);
    int s = rp[wid], e = rp[wid + 1];
    const int* ei = eidx + (size_t)r * E;
    const float* xr = x + (size_t)rr * xrstride;
    float p = 0.f;
    int i = s;
    int e8 = s + ((e - s) & ~7);
    for (; i < e8; i += 8) {
      float a0 = xr[(size_t)ei[i + 0] * D + lane];
      float a1 = xr[(size_t)ei[i + 1] * D + lane];
      float a2 = xr[(size_t)ei[i + 2] * D + lane];
      float a3 = xr[(size_t)ei[i + 3] * D + lane];
      float a4 = xr[(size_t)ei[i + 4] * D + lane];
      float a5 = xr[(size_t)ei[i + 5] * D + lane];
      float a6 = xr[(size_t)ei[i + 6] * D + lane];
      float a7 = xr[(size_t)ei[i + 7] * D + lane];
      p += ((a0 + a1) + (a2 + a3)) + ((a4 + a5) + (a6 + a7));
    }
    for (; i < e; i++) p += xr[(size_t)ei[i] * D + lane];
    sum += p * invdeg[(size_t)r * Nn + wid];
  }
  size_t oo = (size_t)wid * D + lane;
  if (flags & F_ACC) sum += acc[oo];
  if (flags & F_BIAS) sum += bias[lane];
  if (flags & F_RELU) sum = fmaxf(sum, 0.f);
  acc[oo] = sum;
}

// Tiled f32 GEMM, batched over blockIdx.z: C[z][M,Nd] = A[M,K] @ B[z][K,Nd].
// 64x64 tile, 256 threads, 4x4/thread.
__global__ __launch_bounds__(256) void gemm_f32_k(const float* __restrict__ A,
                                                  const float* __restrict__ B,
                                                  float* __restrict__ Cc,
                                                  int M, int K, int Nd,
                                                  long strideB, long strideC) {
  __shared__ float As[64][17];
  __shared__ float Bs[16][64];
  int z = blockIdx.z;
  const float* Bz = B + (size_t)z * strideB;
  float* Cz = Cc + (size_t)z * strideC;
  int tid = threadIdx.x;
  int tx = tid & 15;
  int ty = tid >> 4;
  int rowBase = blockIdx.y * 64;
  int colBase = blockIdx.x * 64;
  float c[4][4] = {};
  for (int k0 = 0; k0 < K; k0 += 16) {
    {
      int rr = tid >> 2;
      int kk = (tid & 3) * 4;
      int gr = rowBase + rr;
      float4 v = {0.f, 0.f, 0.f, 0.f};
      if (gr < M) v = *reinterpret_cast<const float4*>(A + (size_t)gr * K + k0 + kk);
      As[rr][kk] = v.x; As[rr][kk + 1] = v.y; As[rr][kk + 2] = v.z; As[rr][kk + 3] = v.w;
    }
    {
      int kr = tid >> 4;
      int cc = (tid & 15) * 4;
      float4 v = *reinterpret_cast<const float4*>(Bz + (size_t)(k0 + kr) * Nd + colBase + cc);
      *reinterpret_cast<float4*>(&Bs[kr][cc]) = v;
    }
    __syncthreads();
#pragma unroll
    for (int k = 0; k < 16; k++) {
      float a[4], b[4];
#pragma unroll
      for (int i = 0; i < 4; i++) a[i] = As[ty * 4 + i][k];
#pragma unroll
      for (int j = 0; j < 4; j++) b[j] = Bs[k][tx * 4 + j];
#pragma unroll
      for (int i = 0; i < 4; i++)
#pragma unroll
        for (int j = 0; j < 4; j++) c[i][j] += a[i] * b[j];
    }
    __syncthreads();
  }
  for (int i = 0; i < 4; i++) {
    int gr = rowBase + ty * 4 + i;
    if (gr < M) {
      float4 v; v.x = c[i][0]; v.y = c[i][1]; v.z = c[i][2]; v.w = c[i][3];
      *reinterpret_cast<float4*>(Cz + (size_t)gr * Nd + colBase + tx * 4) = v;
    }
  }
}

extern "C" void kernel_launch(void* const* d_in, const int* in_sizes, int n_in,
                              void* d_out, int out_size, void* d_ws, size_t ws_size,
                              hipStream_t stream) {
  const float* embed = (const float*)d_in[0];
  const int* src     = (const int*)d_in[1];
  const int* dst     = (const int*)d_in[2];
  const float* b0    = (const float*)d_in[3];
  const float* w1    = (const float*)d_in[4];
  const float* b1    = (const float*)d_in[5];
  const float* w_out = (const float*)d_in[6];
  const float* b_out = (const float*)d_in[7];
  float* out = (float*)d_out;

  const int D = in_sizes[3];            // 256
  const int C = in_sizes[7];            // 64
  const int N = in_sizes[0] / D;        // 50000
  const int R = in_sizes[4] / (D * D);  // 4
  const int E = in_sizes[1] / R;        // 400000
  const int RE = R * E;

  // ---- workspace layout (tiered by available size) ----
  auto align256 = [](size_t b) { return (b + 255) & ~(size_t)255; };
  size_t sz_h    = align256((size_t)N * D * 4);
  size_t sz_csr  = align256((size_t)R * N * 4) * 3 +          // invdeg, degcnt, cursor
                   align256((size_t)R * (N + 1) * 4) +        // rowptr
                   align256((size_t)RE * 4);                  // eidx
  size_t base = sz_h * 2 + sz_csr;                            // h, h2, CSR
  int RB = 1;                                                 // relation batch width
  if (ws_size >= base + 4 * sz_h) RB = 4;
  else if (ws_size >= base + 2 * sz_h) RB = 2;

  char* w = (char*)d_ws;
  size_t off = 0;
  auto carve = [&](size_t bytes) -> void* {
    void* p = w + off;
    off += align256(bytes);
    return p;
  };
  float* h      = (float*)carve((size_t)N * D * 4);
  float* h2     = (float*)carve((size_t)N * D * 4);
  float* invdeg = (float*)carve((size_t)R * N * 4);
  int* degcnt   = (int*)carve((size_t)R * N * 4);
  int* rowptr   = (int*)carve((size_t)R * (N + 1) * 4);
  int* cursor   = (int*)carve((size_t)R * N * 4);
  int* eidx     = (int*)carve((size_t)RE * 4);
  float* t      = (float*)carve((size_t)RB * N * D * 4);      // per-batch GEMM outputs
  (void)n_in; (void)out_size;

  // --- build CSR (per call; graph shared by all 3 layers) ---
  hipMemsetAsync(degcnt, 0, (size_t)R * N * 4, stream);
  deg_count_k<<<(RE + 255) / 256, 256, 0, stream>>>(dst, RE, E, N, degcnt);
  scan_k<<<R, 1024, 0, stream>>>(degcnt, N, rowptr, cursor, invdeg);
  fill_k<<<(RE + 255) / 256, 256, 0, stream>>>(src, dst, RE, E, N, cursor, eidx);

  int pullBlocks = (N * 64 + 255) / 256;

  // --- layer 0: h = relu(b0 + sum_r agg_r(embed)) --- (single fused pull)
  pull256_k<<<pullBlocks, 256, 0, stream>>>(embed, 0, D, eidx, E, rowptr, invdeg,
                                            R, 0, N, h, b0, F_BIAS | F_RELU);

  // --- layer 1: h2 = relu(b1 + sum_r agg_r(h @ w1[r])) ---
  for (int r0 = 0; r0 < R; r0 += RB) {
    dim3 g(D / 64, (N + 63) / 64, RB);
    gemm_f32_k<<<g, 256, 0, stream>>>(h, w1 + (size_t)r0 * D * D, t, N, D, D,
                                      (long)D * D, (long)N * D);
    int fl = (r0 ? F_ACC : 0) |
             (r0 + RB >= R ? (F_BIAS | F_RELU) : 0);
    pull256_k<<<pullBlocks, 256, 0, stream>>>(t, (long)N * D, D, eidx, E, rowptr,
                                              invdeg, RB, r0, N, h2, b1, fl);
  }

  // --- layer 2: out = b_out + sum_r agg_r(h2 @ w_out[r]) --- (t64 aliases t)
  float* t64 = t;
  for (int r0 = 0; r0 < R; r0 += RB) {
    dim3 g(C / 64, (N + 63) / 64, RB);
    gemm_f32_k<<<g, 256, 0, stream>>>(h2, w_out + (size_t)r0 * D * C, t64, N, D, C,
                                      (long)D * C, (long)N * C);
    int fl = (r0 ? F_ACC : F_BIAS);
    pull64_k<<<pullBlocks, 256, 0, stream>>>(t64, (long)N * C, C, eidx, E, rowptr,
                                             invdeg, RB, r0, N, out, b_out, fl);
  }
}

// Round 3
// 1224.025 us; speedup vs baseline: 1.2574x; 1.1272x over previous
//
#include <hip/hip_runtime.h>

// RGCN node classification: 3 layers of per-relation mean aggregation.
// CSR build once per call; pull-aggregation (no atomics); matmul-first
// (agg_r(h@W) == agg_r(h)@W). All relations fused into ONE pull per layer
// (profile: pull cost is per-dispatch, not per-relation). Layer-1 GEMM
// output stored bf16 so 4 relation buffers fit in workspace.

enum { F_ACC = 1, F_RELU = 2, F_BIAS = 4 };

__device__ inline float bf2f(unsigned s) { return __uint_as_float(s << 16); }
__device__ inline unsigned short f2bf(float f) {
  unsigned u = __float_as_uint(f);
  u += 0x7FFF + ((u >> 16) & 1);  // round-to-nearest-even
  return (unsigned short)(u >> 16);
}

__global__ void deg_count_k(const int* __restrict__ dst, int RE, int E, int Nn,
                            int* __restrict__ degcnt) {
  int g = blockIdx.x * blockDim.x + threadIdx.x;
  if (g < RE) {
    int r = g / E;
    atomicAdd(&degcnt[(size_t)r * Nn + dst[g]], 1);
  }
}

// One block (1024 threads) per relation: exclusive scan of degcnt -> rowptr,
// init cursor, compute invdeg = 1/max(deg,1).
__global__ __launch_bounds__(1024) void scan_k(const int* __restrict__ degcnt, int Nn,
                                               int* __restrict__ rowptr,
                                               int* __restrict__ cursor,
                                               float* __restrict__ invdeg) {
  __shared__ int part[1024];
  int r = blockIdx.x;
  const int* d = degcnt + (size_t)r * Nn;
  int chunk = (Nn + 1023) >> 10;
  int t = threadIdx.x;
  int begin = t * chunk;
  int end = begin + chunk; if (end > Nn) end = Nn;
  int s = 0;
  for (int i = begin; i < end; i++) s += d[i];
  part[t] = s;
  __syncthreads();
  for (int off = 1; off < 1024; off <<= 1) {
    int v = (t >= off) ? part[t - off] : 0;
    __syncthreads();
    part[t] += v;
    __syncthreads();
  }
  int run = (t == 0) ? 0 : part[t - 1];
  int* rp = rowptr + (size_t)r * (Nn + 1);
  for (int i = begin; i < end; i++) {
    int dd = d[i];
    rp[i] = run;
    cursor[(size_t)r * Nn + i] = run;
    invdeg[(size_t)r * Nn + i] = 1.0f / (float)(dd > 0 ? dd : 1);
    run += dd;
  }
  if (t == 1023) rp[Nn] = part[1023];
}

__global__ void fill_k(const int* __restrict__ src, const int* __restrict__ dst,
                       int RE, int E, int Nn,
                       int* __restrict__ cursor, int* __restrict__ eidx) {
  int g = blockIdx.x * blockDim.x + threadIdx.x;
  if (g < RE) {
    int r = g / E;
    int pos = atomicAdd(&cursor[(size_t)r * Nn + dst[g]], 1);
    eidx[(size_t)r * E + pos] = src[g];
  }
}

// Pull aggregation, f32 table, D=256: one wave per node, lane holds float4.
__global__ __launch_bounds__(256) void pull256_k(
    const float* __restrict__ x, long xrstride, int D,
    const int* __restrict__ eidx, int E,
    const int* __restrict__ rowptr, const float* __restrict__ invdeg,
    int nrel, int rel0, int Nn,
    float* __restrict__ acc, const float* __restrict__ bias, int flags) {
  int wid = (blockIdx.x * blockDim.x + threadIdx.x) >> 6;
  if (wid >= Nn) return;
  int lane = threadIdx.x & 63;
  int col4 = lane << 2;
  float sx = 0.f, sy = 0.f, sz = 0.f, sw = 0.f;
  for (int rr = 0; rr < nrel; rr++) {
    int r = rel0 + rr;
    const int* rp = rowptr + (size_t)r * (Nn + 1);
    int s = rp[wid], e = rp[wid + 1];
    const int* ei = eidx + (size_t)r * E;
    const float* xr = x + (size_t)rr * xrstride;
    float px = 0.f, py = 0.f, pz = 0.f, pw = 0.f;
    int i = s;
    int e4 = s + ((e - s) & ~3);
    for (; i < e4; i += 4) {
      int n0 = ei[i + 0], n1 = ei[i + 1], n2 = ei[i + 2], n3 = ei[i + 3];
      const float4 v0 = *reinterpret_cast<const float4*>(xr + (size_t)n0 * D + col4);
      const float4 v1 = *reinterpret_cast<const float4*>(xr + (size_t)n1 * D + col4);
      const float4 v2 = *reinterpret_cast<const float4*>(xr + (size_t)n2 * D + col4);
      const float4 v3 = *reinterpret_cast<const float4*>(xr + (size_t)n3 * D + col4);
      px += (v0.x + v1.x) + (v2.x + v3.x);
      py += (v0.y + v1.y) + (v2.y + v3.y);
      pz += (v0.z + v1.z) + (v2.z + v3.z);
      pw += (v0.w + v1.w) + (v2.w + v3.w);
    }
    for (; i < e; i++) {
      int sn = ei[i];
      const float4 v = *reinterpret_cast<const float4*>(xr + (size_t)sn * D + col4);
      px += v.x; py += v.y; pz += v.z; pw += v.w;
    }
    float w = invdeg[(size_t)r * Nn + wid];
    sx += px * w; sy += py * w; sz += pz * w; sw += pw * w;
  }
  size_t o = (size_t)wid * D + col4;
  if (flags & F_ACC) {
    const float4 p = *reinterpret_cast<const float4*>(acc + o);
    sx += p.x; sy += p.y; sz += p.z; sw += p.w;
  }
  if (flags & F_BIAS) {
    const float4 b = *reinterpret_cast<const float4*>(bias + col4);
    sx += b.x; sy += b.y; sz += b.z; sw += b.w;
  }
  if (flags & F_RELU) {
    sx = fmaxf(sx, 0.f); sy = fmaxf(sy, 0.f); sz = fmaxf(sz, 0.f); sw = fmaxf(sw, 0.f);
  }
  float4 ov; ov.x = sx; ov.y = sy; ov.z = sz; ov.w = sw;
  *reinterpret_cast<float4*>(acc + o) = ov;
}

// Pull aggregation, bf16 table, D=256: lane gathers 8B (4 bf16), f32 accum.
__global__ __launch_bounds__(256) void pull256b_k(
    const unsigned short* __restrict__ x, long xrstride, int D,
    const int* __restrict__ eidx, int E,
    const int* __restrict__ rowptr, const float* __restrict__ invdeg,
    int nrel, int rel0, int Nn,
    float* __restrict__ acc, const float* __restrict__ bias, int flags) {
  int wid = (blockIdx.x * blockDim.x + threadIdx.x) >> 6;
  if (wid >= Nn) return;
  int lane = threadIdx.x & 63;
  int col4 = lane << 2;
  float sx = 0.f, sy = 0.f, sz = 0.f, sw = 0.f;
  for (int rr = 0; rr < nrel; rr++) {
    int r = rel0 + rr;
    const int* rp = rowptr + (size_t)r * (Nn + 1);
    int s = rp[wid], e = rp[wid + 1];
    const int* ei = eidx + (size_t)r * E;
    const unsigned short* xr = x + (size_t)rr * xrstride;
    float px = 0.f, py = 0.f, pz = 0.f, pw = 0.f;
    int i = s;
    int e4 = s + ((e - s) & ~3);
    for (; i < e4; i += 4) {
      int n0 = ei[i + 0], n1 = ei[i + 1], n2 = ei[i + 2], n3 = ei[i + 3];
      const uint2 v0 = *reinterpret_cast<const uint2*>(xr + (size_t)n0 * D + col4);
      const uint2 v1 = *reinterpret_cast<const uint2*>(xr + (size_t)n1 * D + col4);
      const uint2 v2 = *reinterpret_cast<const uint2*>(xr + (size_t)n2 * D + col4);
      const uint2 v3 = *reinterpret_cast<const uint2*>(xr + (size_t)n3 * D + col4);
      px += (bf2f(v0.x & 0xffffu) + bf2f(v1.x & 0xffffu)) +
            (bf2f(v2.x & 0xffffu) + bf2f(v3.x & 0xffffu));
      py += (bf2f(v0.x >> 16) + bf2f(v1.x >> 16)) +
            (bf2f(v2.x >> 16) + bf2f(v3.x >> 16));
      pz += (bf2f(v0.y & 0xffffu) + bf2f(v1.y & 0xffffu)) +
            (bf2f(v2.y & 0xffffu) + bf2f(v3.y & 0xffffu));
      pw += (bf2f(v0.y >> 16) + bf2f(v1.y >> 16)) +
            (bf2f(v2.y >> 16) + bf2f(v3.y >> 16));
    }
    for (; i < e; i++) {
      const uint2 v = *reinterpret_cast<const uint2*>(xr + (size_t)ei[i] * D + col4);
      px += bf2f(v.x & 0xffffu); py += bf2f(v.x >> 16);
      pz += bf2f(v.y & 0xffffu); pw += bf2f(v.y >> 16);
    }
    float w = invdeg[(size_t)r * Nn + wid];
    sx += px * w; sy += py * w; sz += pz * w; sw += pw * w;
  }
  size_t o = (size_t)wid * D + col4;
  if (flags & F_BIAS) {
    const float4 b = *reinterpret_cast<const float4*>(bias + col4);
    sx += b.x; sy += b.y; sz += b.z; sw += b.w;
  }
  if (flags & F_RELU) {
    sx = fmaxf(sx, 0.f); sy = fmaxf(sy, 0.f); sz = fmaxf(sz, 0.f); sw = fmaxf(sw, 0.f);
  }
  float4 ov; ov.x = sx; ov.y = sy; ov.z = sz; ov.w = sw;
  *reinterpret_cast<float4*>(acc + o) = ov;
}

// Pull aggregation, f32 table, D=64: one wave per node, lane holds one float.
__global__ __launch_bounds__(256) void pull64_k(
    const float* __restrict__ x, long xrstride, int D,
    const int* __restrict__ eidx, int E,
    const int* __restrict__ rowptr, const float* __restrict__ invdeg,
    int nrel, int rel0, int Nn,
    float* __restrict__ acc, const float* __restrict__ bias, int flags) {
  int wid = (blockIdx.x * blockDim.x + threadIdx.x) >> 6;
  if (wid >= Nn) return;
  int lane = threadIdx.x & 63;
  float sum = 0.f;
  for (int rr = 0; rr < nrel; rr++) {
    int r = rel0 + rr;
    const int* rp = rowptr + (size_t)r * (Nn + 1);
    int s = rp[wid], e = rp[wid + 1];
    const int* ei = eidx + (size_t)r * E;
    const float* xr = x + (size_t)rr * xrstride;
    float p = 0.f;
    int i = s;
    int e8 = s + ((e - s) & ~7);
    for (; i < e8; i += 8) {
      float a0 = xr[(size_t)ei[i + 0] * D + lane];
      float a1 = xr[(size_t)ei[i + 1] * D + lane];
      float a2 = xr[(size_t)ei[i + 2] * D + lane];
      float a3 = xr[(size_t)ei[i + 3] * D + lane];
      float a4 = xr[(size_t)ei[i + 4] * D + lane];
      float a5 = xr[(size_t)ei[i + 5] * D + lane];
      float a6 = xr[(size_t)ei[i + 6] * D + lane];
      float a7 = xr[(size_t)ei[i + 7] * D + lane];
      p += ((a0 + a1) + (a2 + a3)) + ((a4 + a5) + (a6 + a7));
    }
    for (; i < e; i++) p += xr[(size_t)ei[i] * D + lane];
    sum += p * invdeg[(size_t)r * Nn + wid];
  }
  size_t oo = (size_t)wid * D + lane;
  if (flags & F_ACC) sum += acc[oo];
  if (flags & F_BIAS) sum += bias[lane];
  if (flags & F_RELU) sum = fmaxf(sum, 0.f);
  acc[oo] = sum;
}

// Tiled f32 GEMM, batched over blockIdx.z: C[z][M,Nd] = A[M,K] @ B[z][K,Nd].
// 64x64 tile, 256 threads, 4x4/thread. Optional bf16 store.
__global__ __launch_bounds__(256) void gemm_f32_k(const float* __restrict__ A,
                                                  const float* __restrict__ B,
                                                  void* __restrict__ Cc,
                                                  int M, int K, int Nd,
                                                  long strideB, long strideC,
                                                  int storeBf16) {
  __shared__ float As[64][17];
  __shared__ float Bs[16][64];
  int z = blockIdx.z;
  const float* Bz = B + (size_t)z * strideB;
  int tid = threadIdx.x;
  int tx = tid & 15;
  int ty = tid >> 4;
  int rowBase = blockIdx.y * 64;
  int colBase = blockIdx.x * 64;
  float c[4][4] = {};
  for (int k0 = 0; k0 < K; k0 += 16) {
    {
      int rr = tid >> 2;
      int kk = (tid & 3) * 4;
      int gr = rowBase + rr;
      float4 v = {0.f, 0.f, 0.f, 0.f};
      if (gr < M) v = *reinterpret_cast<const float4*>(A + (size_t)gr * K + k0 + kk);
      As[rr][kk] = v.x; As[rr][kk + 1] = v.y; As[rr][kk + 2] = v.z; As[rr][kk + 3] = v.w;
    }
    {
      int kr = tid >> 4;
      int cc = (tid & 15) * 4;
      float4 v = *reinterpret_cast<const float4*>(Bz + (size_t)(k0 + kr) * Nd + colBase + cc);
      *reinterpret_cast<float4*>(&Bs[kr][cc]) = v;
    }
    __syncthreads();
#pragma unroll
    for (int k = 0; k < 16; k++) {
      float a[4], b[4];
#pragma unroll
      for (int i = 0; i < 4; i++) a[i] = As[ty * 4 + i][k];
#pragma unroll
      for (int j = 0; j < 4; j++) b[j] = Bs[k][tx * 4 + j];
#pragma unroll
      for (int i = 0; i < 4; i++)
#pragma unroll
        for (int j = 0; j < 4; j++) c[i][j] += a[i] * b[j];
    }
    __syncthreads();
  }
  for (int i = 0; i < 4; i++) {
    int gr = rowBase + ty * 4 + i;
    if (gr >= M) continue;
    if (storeBf16) {
      unsigned short* Cz = (unsigned short*)Cc + (size_t)z * strideC;
      ushort4 v4;
      v4.x = f2bf(c[i][0]); v4.y = f2bf(c[i][1]);
      v4.z = f2bf(c[i][2]); v4.w = f2bf(c[i][3]);
      *reinterpret_cast<ushort4*>(Cz + (size_t)gr * Nd + colBase + tx * 4) = v4;
    } else {
      float* Cz = (float*)Cc + (size_t)z * strideC;
      float4 v; v.x = c[i][0]; v.y = c[i][1]; v.z = c[i][2]; v.w = c[i][3];
      *reinterpret_cast<float4*>(Cz + (size_t)gr * Nd + colBase + tx * 4) = v;
    }
  }
}

extern "C" void kernel_launch(void* const* d_in, const int* in_sizes, int n_in,
                              void* d_out, int out_size, void* d_ws, size_t ws_size,
                              hipStream_t stream) {
  const float* embed = (const float*)d_in[0];
  const int* src     = (const int*)d_in[1];
  const int* dst     = (const int*)d_in[2];
  const float* b0    = (const float*)d_in[3];
  const float* w1    = (const float*)d_in[4];
  const float* b1    = (const float*)d_in[5];
  const float* w_out = (const float*)d_in[6];
  const float* b_out = (const float*)d_in[7];
  float* out = (float*)d_out;

  const int D = in_sizes[3];            // 256
  const int C = in_sizes[7];            // 64
  const int N = in_sizes[0] / D;        // 50000
  const int R = in_sizes[4] / (D * D);  // 4
  const int E = in_sizes[1] / R;        // 400000
  const int RE = R * E;

  char* w = (char*)d_ws;
  size_t off = 0;
  auto carve = [&](size_t bytes) -> void* {
    void* p = w + off;
    off += (bytes + 255) & ~(size_t)255;
    return p;
  };
  // Total ~163 MB: h(51.2) + t(102.4) + CSR(~9.6). h2 aliases h; t64 aliases t.
  float* h           = (float*)carve((size_t)N * D * 4);
  unsigned short* t  = (unsigned short*)carve((size_t)R * N * D * 2);
  float* invdeg      = (float*)carve((size_t)R * N * 4);
  int* degcnt        = (int*)carve((size_t)R * N * 4);
  int* rowptr        = (int*)carve((size_t)R * (N + 1) * 4);
  int* cursor        = (int*)carve((size_t)R * N * 4);
  int* eidx          = (int*)carve((size_t)RE * 4);
  float* h2  = h;         // h dead after layer-1 GEMMs
  float* t64 = (float*)t; // t dead after layer-1 pull; needs R*N*C*4 = 51.2 MB
  (void)n_in; (void)out_size; (void)ws_size;

  // --- build CSR (per call; graph shared by all 3 layers) ---
  hipMemsetAsync(degcnt, 0, (size_t)R * N * 4, stream);
  deg_count_k<<<(RE + 255) / 256, 256, 0, stream>>>(dst, RE, E, N, degcnt);
  scan_k<<<R, 1024, 0, stream>>>(degcnt, N, rowptr, cursor, invdeg);
  fill_k<<<(RE + 255) / 256, 256, 0, stream>>>(src, dst, RE, E, N, cursor, eidx);

  int pullBlocks = (N * 64 + 255) / 256;

  // --- layer 0: h = relu(b0 + sum_r agg_r(embed)) ---
  pull256_k<<<pullBlocks, 256, 0, stream>>>(embed, 0, D, eidx, E, rowptr, invdeg,
                                            R, 0, N, h, b0, F_BIAS | F_RELU);

  // --- layer 1: t[r] = h @ w1[r] (bf16); h2 = relu(b1 + sum_r agg_r(t[r])) ---
  {
    dim3 g(D / 64, (N + 63) / 64, R);
    gemm_f32_k<<<g, 256, 0, stream>>>(h, w1, (void*)t, N, D, D,
                                      (long)D * D, (long)N * D, 1);
    pull256b_k<<<pullBlocks, 256, 0, stream>>>(t, (long)N * D, D, eidx, E, rowptr,
                                               invdeg, R, 0, N, h2, b1,
                                               F_BIAS | F_RELU);
  }

  // --- layer 2: t64[r] = h2 @ w_out[r]; out = b_out + sum_r agg_r(t64[r]) ---
  {
    dim3 g(C / 64, (N + 63) / 64, R);
    gemm_f32_k<<<g, 256, 0, stream>>>(h2, w_out, (void*)t64, N, D, C,
                                      (long)D * C, (long)N * C, 0);
    pull64_k<<<pullBlocks, 256, 0, stream>>>(t64, (long)N * C, C, eidx, E, rowptr,
                                             invdeg, R, 0, N, out, b_out, F_BIAS);
  }
}

// Round 4
// 824.207 us; speedup vs baseline: 1.8673x; 1.4851x over previous
//
#include <hip/hip_runtime.h>

// RGCN node classification, restructured:
//   layer0: h    = relu(b0 + sum_r agg_r(embed))                       [pull-sum]
//   layer1: h2   = relu(b1 + concat_r(agg_r(h)) @ vstack(w1))          [pull-rel + MFMA GEMM K=1024]
//   layer2: out  = b_out + concat_r(agg_r(h2)) @ vstack(w_out)         [pull-rel + MFMA GEMM K=1024]
// CSR built once per call; all gather tables bf16; GEMMs bf16 MFMA, f32 accum.

typedef unsigned short ushort_t;
using f32x4  = __attribute__((ext_vector_type(4))) float;
using short8 = __attribute__((ext_vector_type(8))) short;

__device__ inline float bf2f(unsigned s) { return __uint_as_float(s << 16); }
__device__ inline unsigned short f2bf(float f) {
  unsigned u = __float_as_uint(f);
  u += 0x7FFF + ((u >> 16) & 1);  // round-to-nearest-even
  return (unsigned short)(u >> 16);
}

// ---------------- CSR build ----------------
__global__ void deg_count_k(const int* __restrict__ dst, int RE, int E, int Nn,
                            int* __restrict__ degcnt) {
  int g = blockIdx.x * blockDim.x + threadIdx.x;
  if (g < RE) {
    int r = g / E;
    atomicAdd(&degcnt[(size_t)r * Nn + dst[g]], 1);
  }
}

// One block (1024 threads) per relation. NOTE: degcnt and cursor may alias
// (in-place): each element is read before it is overwritten by the same thread.
__global__ __launch_bounds__(1024) void scan_k(const int* degcnt, int Nn,
                                               int* __restrict__ rowptr,
                                               int* cursor,
                                               float* __restrict__ invdeg) {
  __shared__ int part[1024];
  int r = blockIdx.x;
  const int* d = degcnt + (size_t)r * Nn;
  int chunk = (Nn + 1023) >> 10;
  int t = threadIdx.x;
  int begin = t * chunk;
  int end = begin + chunk; if (end > Nn) end = Nn;
  int s = 0;
  for (int i = begin; i < end; i++) s += d[i];
  part[t] = s;
  __syncthreads();
  for (int off = 1; off < 1024; off <<= 1) {
    int v = (t >= off) ? part[t - off] : 0;
    __syncthreads();
    part[t] += v;
    __syncthreads();
  }
  int run = (t == 0) ? 0 : part[t - 1];
  int* rp = rowptr + (size_t)r * (Nn + 1);
  for (int i = begin; i < end; i++) {
    int dd = d[i];
    rp[i] = run;
    cursor[(size_t)r * Nn + i] = run;
    invdeg[(size_t)r * Nn + i] = 1.0f / (float)(dd > 0 ? dd : 1);
    run += dd;
  }
  if (t == 1023) rp[Nn] = part[1023];
}

__global__ void fill_k(const int* __restrict__ src, const int* __restrict__ dst,
                       int RE, int E, int Nn,
                       int* __restrict__ cursor, int* __restrict__ eidx) {
  int g = blockIdx.x * blockDim.x + threadIdx.x;
  if (g < RE) {
    int r = g / E;
    int pos = atomicAdd(&cursor[(size_t)r * Nn + dst[g]], 1);
    eidx[(size_t)r * E + pos] = src[g];
  }
}

// ---------------- prep: f32 -> bf16, weight transpose ----------------
__global__ void f2bf_vec_k(const float* __restrict__ in, ushort_t* __restrict__ out,
                           long n4) {
  long i = (long)blockIdx.x * blockDim.x + threadIdx.x;
  if (i < n4) {
    float4 v = *reinterpret_cast<const float4*>(in + i * 4);
    ushort4 o; o.x = f2bf(v.x); o.y = f2bf(v.y); o.z = f2bf(v.z); o.w = f2bf(v.w);
    *reinterpret_cast<ushort4*>(out + i * 4) = o;
  }
}

// wt[j][rk] = (bf16) w[rk][j];  w: [RD][Nd] f32, wt: [Nd][RD] bf16.
__global__ void wtrans_k(const float* __restrict__ w, ushort_t* __restrict__ wt,
                         int RD, int Nd) {
  int tid = blockIdx.x * blockDim.x + threadIdx.x;
  if (tid < RD * Nd) {
    int rk = tid % RD;
    int j  = tid / RD;
    wt[(size_t)j * RD + rk] = f2bf(w[(size_t)rk * Nd + j]);
  }
}

// ---------------- pulls (bf16 table, D=256, wave per node) ----------------
// layer 0: sum over relations, + bias, relu, bf16 out [Nn][256]
__global__ __launch_bounds__(256) void pull_sum_bf_k(
    const ushort_t* __restrict__ x,
    const int* __restrict__ eidx, int E,
    const int* __restrict__ rowptr, const float* __restrict__ invdeg,
    int R, int Nn, ushort_t* __restrict__ out, const float* __restrict__ bias) {
  int wid = (blockIdx.x * blockDim.x + threadIdx.x) >> 6;
  if (wid >= Nn) return;
  int lane = threadIdx.x & 63;
  int col4 = lane << 2;
  const int D = 256;
  float sx = 0.f, sy = 0.f, sz = 0.f, sw = 0.f;
  for (int r = 0; r < R; r++) {
    const int* rp = rowptr + (size_t)r * (Nn + 1);
    int s = rp[wid], e = rp[wid + 1];
    const int* ei = eidx + (size_t)r * E;
    float px = 0.f, py = 0.f, pz = 0.f, pw = 0.f;
    int i = s;
    int e4 = s + ((e - s) & ~3);
    for (; i < e4; i += 4) {
      int n0 = ei[i], n1 = ei[i + 1], n2 = ei[i + 2], n3 = ei[i + 3];
      const uint2 v0 = *reinterpret_cast<const uint2*>(x + (size_t)n0 * D + col4);
      const uint2 v1 = *reinterpret_cast<const uint2*>(x + (size_t)n1 * D + col4);
      const uint2 v2 = *reinterpret_cast<const uint2*>(x + (size_t)n2 * D + col4);
      const uint2 v3 = *reinterpret_cast<const uint2*>(x + (size_t)n3 * D + col4);
      px += (bf2f(v0.x & 0xffffu) + bf2f(v1.x & 0xffffu)) +
            (bf2f(v2.x & 0xffffu) + bf2f(v3.x & 0xffffu));
      py += (bf2f(v0.x >> 16) + bf2f(v1.x >> 16)) +
            (bf2f(v2.x >> 16) + bf2f(v3.x >> 16));
      pz += (bf2f(v0.y & 0xffffu) + bf2f(v1.y & 0xffffu)) +
            (bf2f(v2.y & 0xffffu) + bf2f(v3.y & 0xffffu));
      pw += (bf2f(v0.y >> 16) + bf2f(v1.y >> 16)) +
            (bf2f(v2.y >> 16) + bf2f(v3.y >> 16));
    }
    for (; i < e; i++) {
      const uint2 v = *reinterpret_cast<const uint2*>(x + (size_t)ei[i] * D + col4);
      px += bf2f(v.x & 0xffffu); py += bf2f(v.x >> 16);
      pz += bf2f(v.y & 0xffffu); pw += bf2f(v.y >> 16);
    }
    float w = invdeg[(size_t)r * Nn + wid];
    sx += px * w; sy += py * w; sz += pz * w; sw += pw * w;
  }
  const float4 b = *reinterpret_cast<const float4*>(bias + col4);
  sx = fmaxf(sx + b.x, 0.f); sy = fmaxf(sy + b.y, 0.f);
  sz = fmaxf(sz + b.z, 0.f); sw = fmaxf(sw + b.w, 0.f);
  ushort4 o; o.x = f2bf(sx); o.y = f2bf(sy); o.z = f2bf(sz); o.w = f2bf(sw);
  *reinterpret_cast<ushort4*>(out + (size_t)wid * D + col4) = o;
}

// layers 1/2 pre-GEMM: per-relation aggregate, bf16 out [Nn][R*256] (K-concat)
__global__ __launch_bounds__(256) void pull_rel_bf_k(
    const ushort_t* __restrict__ x,
    const int* __restrict__ eidx, int E,
    const int* __restrict__ rowptr, const float* __restrict__ invdeg,
    int R, int Nn, ushort_t* __restrict__ out) {
  int wid = (blockIdx.x * blockDim.x + threadIdx.x) >> 6;
  if (wid >= Nn) return;
  int lane = threadIdx.x & 63;
  int col4 = lane << 2;
  const int D = 256;
  for (int r = 0; r < R; r++) {
    const int* rp = rowptr + (size_t)r * (Nn + 1);
    int s = rp[wid], e = rp[wid + 1];
    const int* ei = eidx + (size_t)r * E;
    float px = 0.f, py = 0.f, pz = 0.f, pw = 0.f;
    int i = s;
    int e4 = s + ((e - s) & ~3);
    for (; i < e4; i += 4) {
      int n0 = ei[i], n1 = ei[i + 1], n2 = ei[i + 2], n3 = ei[i + 3];
      const uint2 v0 = *reinterpret_cast<const uint2*>(x + (size_t)n0 * D + col4);
      const uint2 v1 = *reinterpret_cast<const uint2*>(x + (size_t)n1 * D + col4);
      const uint2 v2 = *reinterpret_cast<const uint2*>(x + (size_t)n2 * D + col4);
      const uint2 v3 = *reinterpret_cast<const uint2*>(x + (size_t)n3 * D + col4);
      px += (bf2f(v0.x & 0xffffu) + bf2f(v1.x & 0xffffu)) +
            (bf2f(v2.x & 0xffffu) + bf2f(v3.x & 0xffffu));
      py += (bf2f(v0.x >> 16) + bf2f(v1.x >> 16)) +
            (bf2f(v2.x >> 16) + bf2f(v3.x >> 16));
      pz += (bf2f(v0.y & 0xffffu) + bf2f(v1.y & 0xffffu)) +
            (bf2f(v2.y & 0xffffu) + bf2f(v3.y & 0xffffu));
      pw += (bf2f(v0.y >> 16) + bf2f(v1.y >> 16)) +
            (bf2f(v2.y >> 16) + bf2f(v3.y >> 16));
    }
    for (; i < e; i++) {
      const uint2 v = *reinterpret_cast<const uint2*>(x + (size_t)ei[i] * D + col4);
      px += bf2f(v.x & 0xffffu); py += bf2f(v.x >> 16);
      pz += bf2f(v.y & 0xffffu); pw += bf2f(v.y >> 16);
    }
    float w = invdeg[(size_t)r * Nn + wid];
    ushort4 o;
    o.x = f2bf(px * w); o.y = f2bf(py * w); o.z = f2bf(pz * w); o.w = f2bf(pw * w);
    *reinterpret_cast<ushort4*>(out + (size_t)wid * (R * D) + r * D + col4) = o;
  }
}

// ---------------- bf16 MFMA GEMM ----------------
// C[M][Nd] = A[M][K] @ Bt[Nd][K]^T, + bias, optional relu, f32 or bf16 store.
// Block: 256 threads = 4 waves (2x2). BM=128, BN=FN*32 (FN=4 -> 128, FN=2 -> 64).
// A staged in LDS (pitch 72 bf16 = 144B, 16B-aligned, ~2-way bank aliasing = free).
// Bt fragments loaded directly from global (weights are small, L2-resident).
template <int FN, int STORE_BF16, int RELU>
__global__ __launch_bounds__(256) void gemm_mfma_k(
    const ushort_t* __restrict__ A, const ushort_t* __restrict__ Bt,
    void* __restrict__ Cp, const float* __restrict__ bias,
    int M, int K, int Nd) {
  __shared__ ushort_t Atile[128][72];
  const int tid = threadIdx.x;
  const int lane = tid & 63;
  const int wid = tid >> 6;
  const int wr = wid >> 1;        // wave row (0..1), 64 rows each
  const int wc = wid & 1;         // wave col (0..1), FN*16 cols each
  const int rowBase = blockIdx.y * 128;
  const int colBase = blockIdx.x * (FN * 32);
  const int l15 = lane & 15;
  const int g = lane >> 4;        // 0..3

  f32x4 acc[4][FN] = {};

  const int srow = tid >> 3;      // staging: 0..31
  const int schunk = tid & 7;     // 8 chunks of 8 bf16 per 64-wide K-slab

  for (int k0 = 0; k0 < K; k0 += 64) {
#pragma unroll
    for (int i = 0; i < 4; i++) {
      int row = srow + i * 32;
      int grow = rowBase + row;
      if (grow >= M) grow = M - 1;  // clamp: affects only unstored C rows
      short8 v = *reinterpret_cast<const short8*>(A + (size_t)grow * K + k0 + schunk * 8);
      *reinterpret_cast<short8*>(&Atile[row][schunk * 8]) = v;
    }
    __syncthreads();
#pragma unroll
    for (int kk = 0; kk < 2; kk++) {
      short8 a[4], b[FN];
#pragma unroll
      for (int m = 0; m < 4; m++)
        a[m] = *reinterpret_cast<const short8*>(&Atile[wr * 64 + m * 16 + l15][kk * 32 + g * 8]);
#pragma unroll
      for (int n = 0; n < FN; n++) {
        int col = colBase + wc * (FN * 16) + n * 16 + l15;
        b[n] = *reinterpret_cast<const short8*>(Bt + (size_t)col * K + k0 + kk * 32 + g * 8);
      }
#pragma unroll
      for (int m = 0; m < 4; m++)
#pragma unroll
        for (int n = 0; n < FN; n++)
          acc[m][n] = __builtin_amdgcn_mfma_f32_16x16x32_bf16(a[m], b[n], acc[m][n], 0, 0, 0);
    }
    __syncthreads();
  }

  // epilogue: C/D layout col=lane&15, row=(lane>>4)*4+reg  [guide §3, m89-verified]
#pragma unroll
  for (int n = 0; n < FN; n++) {
    int col = colBase + wc * (FN * 16) + n * 16 + l15;
    float bv = bias[col];
#pragma unroll
    for (int m = 0; m < 4; m++) {
      int row0 = rowBase + wr * 64 + m * 16 + g * 4;
#pragma unroll
      for (int j = 0; j < 4; j++) {
        int row = row0 + j;
        if (row < M) {
          float v = acc[m][n][j] + bv;
          if (RELU) v = fmaxf(v, 0.f);
          if (STORE_BF16)
            ((ushort_t*)Cp)[(size_t)row * Nd + col] = f2bf(v);
          else
            ((float*)Cp)[(size_t)row * Nd + col] = v;
        }
      }
    }
  }
}

extern "C" void kernel_launch(void* const* d_in, const int* in_sizes, int n_in,
                              void* d_out, int out_size, void* d_ws, size_t ws_size,
                              hipStream_t stream) {
  const float* embed = (const float*)d_in[0];
  const int* src     = (const int*)d_in[1];
  const int* dst     = (const int*)d_in[2];
  const float* b0    = (const float*)d_in[3];
  const float* w1    = (const float*)d_in[4];
  const float* b1    = (const float*)d_in[5];
  const float* w_out = (const float*)d_in[6];
  const float* b_out = (const float*)d_in[7];
  float* out = (float*)d_out;

  const int D = in_sizes[3];            // 256
  const int C = in_sizes[7];            // 64
  const int N = in_sizes[0] / D;        // 50000
  const int R = in_sizes[4] / (D * D);  // 4
  const int E = in_sizes[1] / R;        // 400000
  const int RE = R * E;
  const int K = R * D;                  // 1024

  char* w = (char*)d_ws;
  size_t off = 0;
  auto carve = [&](size_t bytes) -> void* {
    void* p = w + off;
    off += (bytes + 255) & ~(size_t)255;
    return p;
  };
  // ~163 MB total
  ushort_t* ebf  = (ushort_t*)carve((size_t)N * D * 2);       // 25.6 MB
  ushort_t* h    = (ushort_t*)carve((size_t)N * D * 2);       // 25.6 MB (reused as h2)
  ushort_t* hagg = (ushort_t*)carve((size_t)N * K * 2);       // 102.4 MB
  ushort_t* w1t  = (ushort_t*)carve((size_t)D * K * 2);       // 0.5 MB
  ushort_t* wot  = (ushort_t*)carve((size_t)C * K * 2);       // 0.13 MB
  float* invdeg  = (float*)carve((size_t)R * N * 4);
  int* rowptr    = (int*)carve((size_t)R * (N + 1) * 4);
  int* cursor    = (int*)carve((size_t)R * N * 4);            // doubles as degcnt
  int* eidx      = (int*)carve((size_t)RE * 4);
  ushort_t* h2 = h;   // h dead after pull_rel(layer1)
  (void)n_in; (void)out_size; (void)ws_size;

  // --- CSR build (graph shared by all 3 layers) ---
  hipMemsetAsync(cursor, 0, (size_t)R * N * 4, stream);
  deg_count_k<<<(RE + 255) / 256, 256, 0, stream>>>(dst, RE, E, N, cursor);
  scan_k<<<R, 1024, 0, stream>>>(cursor, N, rowptr, cursor, invdeg);
  fill_k<<<(RE + 255) / 256, 256, 0, stream>>>(src, dst, RE, E, N, cursor, eidx);

  // --- prep: embed->bf16, weights -> transposed bf16 ---
  long n4 = (long)N * D / 4;
  f2bf_vec_k<<<(int)((n4 + 255) / 256), 256, 0, stream>>>(embed, ebf, n4);
  wtrans_k<<<(K * D + 255) / 256, 256, 0, stream>>>(w1, w1t, K, D);
  wtrans_k<<<(K * C + 255) / 256, 256, 0, stream>>>(w_out, wot, K, C);

  const int pullBlocks = (N * 64 + 255) / 256;

  // --- layer 0: h = relu(b0 + sum_r agg_r(embed)) ---
  pull_sum_bf_k<<<pullBlocks, 256, 0, stream>>>(ebf, eidx, E, rowptr, invdeg,
                                                R, N, h, b0);

  // --- layer 1: hagg = concat_r agg_r(h);  h2 = relu(hagg @ w1cat + b1) ---
  pull_rel_bf_k<<<pullBlocks, 256, 0, stream>>>(h, eidx, E, rowptr, invdeg,
                                                R, N, hagg);
  {
    dim3 grid(D / 128, (N + 127) / 128);
    gemm_mfma_k<4, 1, 1><<<grid, 256, 0, stream>>>(hagg, w1t, (void*)h2, b1, N, K, D);
  }

  // --- layer 2: hagg = concat_r agg_r(h2); out = hagg @ wocat + b_out ---
  pull_rel_bf_k<<<pullBlocks, 256, 0, stream>>>(h2, eidx, E, rowptr, invdeg,
                                                R, N, hagg);
  {
    dim3 grid(C / 64, (N + 127) / 128);
    gemm_mfma_k<2, 0, 0><<<grid, 256, 0, stream>>>(hagg, wot, (void*)out, b_out, N, K, C);
  }
}

// Round 5
// 690.914 us; speedup vs baseline: 2.2275x; 1.1929x over previous
//
#include <hip/hip_runtime.h>

// RGCN node classification:
//   layer0: h    = relu(b0 + sum_r agg_r(embed))                       [pull-sum]
//   layer1: h2   = relu(b1 + concat_r(agg_r(h)) @ vstack(w1))          [pull-rel + MFMA GEMM K=1024]
//   layer2: out  = b_out + concat_r(agg_r(h2)) @ vstack(w_out)         [pull-rel + MFMA GEMM K=1024]
// CSR built once per call via flat 3-phase parallel scan (rowptr contiguous
// across relations since each relation has exactly E edges). All gather
// tables bf16; GEMMs bf16 MFMA with f32 accumulate.

typedef unsigned short ushort_t;
using f32x4  = __attribute__((ext_vector_type(4))) float;
using short8 = __attribute__((ext_vector_type(8))) short;

__device__ inline float bf2f(unsigned s) { return __uint_as_float(s << 16); }
__device__ inline unsigned short f2bf(float f) {
  unsigned u = __float_as_uint(f);
  u += 0x7FFF + ((u >> 16) & 1);  // round-to-nearest-even
  return (unsigned short)(u >> 16);
}

// ---------------- CSR build ----------------
__global__ void deg_count_k(const int* __restrict__ dst, int RE, int E, int Nn,
                            int* __restrict__ degcnt) {
  int g = blockIdx.x * blockDim.x + threadIdx.x;
  if (g < RE) {
    int r = g / E;
    atomicAdd(&degcnt[(size_t)r * Nn + dst[g]], 1);
  }
}

// Phase A: per-block (1024 elems) exclusive scan of degcnt -> rowptr, block sums.
__global__ __launch_bounds__(1024) void scanA_k(const int* __restrict__ degcnt, int M,
                                                int* __restrict__ rowptr,
                                                int* __restrict__ blocksum) {
  __shared__ int sm[1024];
  int t = threadIdx.x;
  int g = blockIdx.x * 1024 + t;
  int v = (g < M) ? degcnt[g] : 0;
  sm[t] = v;
  __syncthreads();
  for (int off = 1; off < 1024; off <<= 1) {
    int u = (t >= off) ? sm[t - off] : 0;
    __syncthreads();
    sm[t] += u;
    __syncthreads();
  }
  if (g < M) rowptr[g] = sm[t] - v;       // in-block exclusive
  if (t == 1023) blocksum[blockIdx.x] = sm[1023];
}

// Phase B: one block scans the block sums (exclusive, in place). nb <= 1024.
__global__ __launch_bounds__(1024) void scanB_k(int* __restrict__ blocksum, int nb) {
  __shared__ int sm[1024];
  int t = threadIdx.x;
  int v = (t < nb) ? blocksum[t] : 0;
  sm[t] = v;
  __syncthreads();
  for (int off = 1; off < 1024; off <<= 1) {
    int u = (t >= off) ? sm[t - off] : 0;
    __syncthreads();
    sm[t] += u;
    __syncthreads();
  }
  if (t < nb) blocksum[t] = sm[t] - v;    // exclusive block offsets
}

// Phase C: add block offset; emit final rowptr, cursor, invdeg.
__global__ __launch_bounds__(1024) void scanC_k(const int* __restrict__ degcnt, int M,
                                                const int* __restrict__ blocksum,
                                                int* __restrict__ rowptr,
                                                int* __restrict__ cursor,
                                                float* __restrict__ invdeg) {
  int g = blockIdx.x * 1024 + threadIdx.x;
  if (g < M) {
    int val = rowptr[g] + blocksum[blockIdx.x];
    int dd = degcnt[g];
    rowptr[g] = val;
    cursor[g] = val;
    invdeg[g] = 1.0f / (float)(dd > 0 ? dd : 1);
    if (g == M - 1) rowptr[M] = val + dd;
  }
}

__global__ void fill_k(const int* __restrict__ src, const int* __restrict__ dst,
                       int RE, int E, int Nn,
                       int* __restrict__ cursor, int* __restrict__ eidx) {
  int g = blockIdx.x * blockDim.x + threadIdx.x;
  if (g < RE) {
    int r = g / E;
    int pos = atomicAdd(&cursor[(size_t)r * Nn + dst[g]], 1);
    eidx[pos] = src[g];                    // flat global position
  }
}

// ---------------- prep: f32 -> bf16, weight transpose ----------------
__global__ void f2bf_vec_k(const float* __restrict__ in, ushort_t* __restrict__ out,
                           long n4) {
  long i = (long)blockIdx.x * blockDim.x + threadIdx.x;
  if (i < n4) {
    float4 v = *reinterpret_cast<const float4*>(in + i * 4);
    ushort4 o; o.x = f2bf(v.x); o.y = f2bf(v.y); o.z = f2bf(v.z); o.w = f2bf(v.w);
    *reinterpret_cast<ushort4*>(out + i * 4) = o;
  }
}

// wt[j][rk] = (bf16) w[rk][j];  w: [RD][Nd] f32, wt: [Nd][RD] bf16.
__global__ void wtrans_k(const float* __restrict__ w, ushort_t* __restrict__ wt,
                         int RD, int Nd) {
  int tid = blockIdx.x * blockDim.x + threadIdx.x;
  if (tid < RD * Nd) {
    int rk = tid % RD;
    int j  = tid / RD;
    wt[(size_t)j * RD + rk] = f2bf(w[(size_t)rk * Nd + j]);
  }
}

// ---------------- pulls (bf16 table, D=256, wave per node) ----------------
// Masked unroll-4 gather: no serial tail; duplicate clamped loads are cheap.
#define GATHER4_BODY                                                          \
  float px = 0.f, py = 0.f, pz = 0.f, pw = 0.f;                               \
  for (int i = s; i < e; i += 4) {                                            \
    int i1 = i + 1 < e ? i + 1 : i;                                           \
    int i2 = i + 2 < e ? i + 2 : i;                                           \
    int i3 = i + 3 < e ? i + 3 : i;                                           \
    float m1 = i + 1 < e ? 1.f : 0.f;                                         \
    float m2 = i + 2 < e ? 1.f : 0.f;                                         \
    float m3 = i + 3 < e ? 1.f : 0.f;                                         \
    int n0 = ei[i], n1 = ei[i1], n2 = ei[i2], n3 = ei[i3];                    \
    const uint2 v0 = *reinterpret_cast<const uint2*>(x + (size_t)n0 * D + col4); \
    const uint2 v1 = *reinterpret_cast<const uint2*>(x + (size_t)n1 * D + col4); \
    const uint2 v2 = *reinterpret_cast<const uint2*>(x + (size_t)n2 * D + col4); \
    const uint2 v3 = *reinterpret_cast<const uint2*>(x + (size_t)n3 * D + col4); \
    px += bf2f(v0.x & 0xffffu) + m1 * bf2f(v1.x & 0xffffu) +                  \
          m2 * bf2f(v2.x & 0xffffu) + m3 * bf2f(v3.x & 0xffffu);              \
    py += bf2f(v0.x >> 16) + m1 * bf2f(v1.x >> 16) +                          \
          m2 * bf2f(v2.x >> 16) + m3 * bf2f(v3.x >> 16);                      \
    pz += bf2f(v0.y & 0xffffu) + m1 * bf2f(v1.y & 0xffffu) +                  \
          m2 * bf2f(v2.y & 0xffffu) + m3 * bf2f(v3.y & 0xffffu);              \
    pw += bf2f(v0.y >> 16) + m1 * bf2f(v1.y >> 16) +                          \
          m2 * bf2f(v2.y >> 16) + m3 * bf2f(v3.y >> 16);                      \
  }

// layer 0: sum over relations, + bias, relu, bf16 out [Nn][256]
__global__ __launch_bounds__(256) void pull_sum_bf_k(
    const ushort_t* __restrict__ x,
    const int* __restrict__ eidx,
    const int* __restrict__ rowptr, const float* __restrict__ invdeg,
    int R, int Nn, ushort_t* __restrict__ out, const float* __restrict__ bias) {
  int wid = (blockIdx.x * blockDim.x + threadIdx.x) >> 6;
  if (wid >= Nn) return;
  int lane = threadIdx.x & 63;
  int col4 = lane << 2;
  const int D = 256;
  const int* ei = eidx;
  float sx = 0.f, sy = 0.f, sz = 0.f, sw = 0.f;
  for (int r = 0; r < R; r++) {
    const int* rp = rowptr + (size_t)r * Nn;   // flat; rp[wid+1] valid at boundary
    int s = rp[wid], e = rp[wid + 1];
    GATHER4_BODY
    float w = invdeg[(size_t)r * Nn + wid];
    sx += px * w; sy += py * w; sz += pz * w; sw += pw * w;
  }
  const float4 b = *reinterpret_cast<const float4*>(bias + col4);
  sx = fmaxf(sx + b.x, 0.f); sy = fmaxf(sy + b.y, 0.f);
  sz = fmaxf(sz + b.z, 0.f); sw = fmaxf(sw + b.w, 0.f);
  ushort4 o; o.x = f2bf(sx); o.y = f2bf(sy); o.z = f2bf(sz); o.w = f2bf(sw);
  *reinterpret_cast<ushort4*>(out + (size_t)wid * D + col4) = o;
}

// layers 1/2 pre-GEMM: per-relation aggregate, bf16 out [Nn][R*256] (K-concat)
__global__ __launch_bounds__(256) void pull_rel_bf_k(
    const ushort_t* __restrict__ x,
    const int* __restrict__ eidx,
    const int* __restrict__ rowptr, const float* __restrict__ invdeg,
    int R, int Nn, ushort_t* __restrict__ out) {
  int wid = (blockIdx.x * blockDim.x + threadIdx.x) >> 6;
  if (wid >= Nn) return;
  int lane = threadIdx.x & 63;
  int col4 = lane << 2;
  const int D = 256;
  const int* ei = eidx;
  for (int r = 0; r < R; r++) {
    const int* rp = rowptr + (size_t)r * Nn;
    int s = rp[wid], e = rp[wid + 1];
    GATHER4_BODY
    float w = invdeg[(size_t)r * Nn + wid];
    ushort4 o;
    o.x = f2bf(px * w); o.y = f2bf(py * w); o.z = f2bf(pz * w); o.w = f2bf(pw * w);
    *reinterpret_cast<ushort4*>(out + (size_t)wid * (R * D) + r * D + col4) = o;
  }
}

// ---------------- bf16 MFMA GEMM ----------------
// C[M][Nd] = A[M][K] @ Bt[Nd][K]^T, + bias, optional relu, f32 or bf16 store.
// Block: 256 threads = 4 waves (2x2). BM=128, BN=FN*32 (FN=4 -> 128, FN=2 -> 64).
// A staged in LDS (pitch 72 bf16 = 144B; ~2-way bank aliasing = free per m136).
// Bt fragments loaded directly from global (weights small, L2-resident).
template <int FN, int STORE_BF16, int RELU>
__global__ __launch_bounds__(256) void gemm_mfma_k(
    const ushort_t* __restrict__ A, const ushort_t* __restrict__ Bt,
    void* __restrict__ Cp, const float* __restrict__ bias,
    int M, int K, int Nd) {
  __shared__ ushort_t Atile[128][72];
  const int tid = threadIdx.x;
  const int lane = tid & 63;
  const int wid = tid >> 6;
  const int wr = wid >> 1;        // wave row (0..1), 64 rows each
  const int wc = wid & 1;         // wave col (0..1), FN*16 cols each
  const int rowBase = blockIdx.y * 128;
  const int colBase = blockIdx.x * (FN * 32);
  const int l15 = lane & 15;
  const int g = lane >> 4;        // 0..3

  f32x4 acc[4][FN] = {};

  const int srow = tid >> 3;      // staging: 0..31
  const int schunk = tid & 7;     // 8 chunks of 8 bf16 per 64-wide K-slab

  for (int k0 = 0; k0 < K; k0 += 64) {
#pragma unroll
    for (int i = 0; i < 4; i++) {
      int row = srow + i * 32;
      int grow = rowBase + row;
      if (grow >= M) grow = M - 1;  // clamp: affects only unstored C rows
      short8 v = *reinterpret_cast<const short8*>(A + (size_t)grow * K + k0 + schunk * 8);
      *reinterpret_cast<short8*>(&Atile[row][schunk * 8]) = v;
    }
    __syncthreads();
#pragma unroll
    for (int kk = 0; kk < 2; kk++) {
      short8 a[4], b[FN];
#pragma unroll
      for (int m = 0; m < 4; m++)
        a[m] = *reinterpret_cast<const short8*>(&Atile[wr * 64 + m * 16 + l15][kk * 32 + g * 8]);
#pragma unroll
      for (int n = 0; n < FN; n++) {
        int col = colBase + wc * (FN * 16) + n * 16 + l15;
        b[n] = *reinterpret_cast<const short8*>(Bt + (size_t)col * K + k0 + kk * 32 + g * 8);
      }
#pragma unroll
      for (int m = 0; m < 4; m++)
#pragma unroll
        for (int n = 0; n < FN; n++)
          acc[m][n] = __builtin_amdgcn_mfma_f32_16x16x32_bf16(a[m], b[n], acc[m][n], 0, 0, 0);
    }
    __syncthreads();
  }

  // epilogue: C/D layout col=lane&15, row=(lane>>4)*4+reg  [guide §3, m89-verified]
#pragma unroll
  for (int n = 0; n < FN; n++) {
    int col = colBase + wc * (FN * 16) + n * 16 + l15;
    float bv = bias[col];
#pragma unroll
    for (int m = 0; m < 4; m++) {
      int row0 = rowBase + wr * 64 + m * 16 + g * 4;
#pragma unroll
      for (int j = 0; j < 4; j++) {
        int row = row0 + j;
        if (row < M) {
          float v = acc[m][n][j] + bv;
          if (RELU) v = fmaxf(v, 0.f);
          if (STORE_BF16)
            ((ushort_t*)Cp)[(size_t)row * Nd + col] = f2bf(v);
          else
            ((float*)Cp)[(size_t)row * Nd + col] = v;
        }
      }
    }
  }
}

extern "C" void kernel_launch(void* const* d_in, const int* in_sizes, int n_in,
                              void* d_out, int out_size, void* d_ws, size_t ws_size,
                              hipStream_t stream) {
  const float* embed = (const float*)d_in[0];
  const int* src     = (const int*)d_in[1];
  const int* dst     = (const int*)d_in[2];
  const float* b0    = (const float*)d_in[3];
  const float* w1    = (const float*)d_in[4];
  const float* b1    = (const float*)d_in[5];
  const float* w_out = (const float*)d_in[6];
  const float* b_out = (const float*)d_in[7];
  float* out = (float*)d_out;

  const int D = in_sizes[3];            // 256
  const int C = in_sizes[7];            // 64
  const int N = in_sizes[0] / D;        // 50000
  const int R = in_sizes[4] / (D * D);  // 4
  const int E = in_sizes[1] / R;        // 400000
  const int RE = R * E;
  const int K = R * D;                  // 1024
  const int M = R * N;                  // scan length

  char* w = (char*)d_ws;
  size_t off = 0;
  auto carve = [&](size_t bytes) -> void* {
    void* p = w + off;
    off += (bytes + 255) & ~(size_t)255;
    return p;
  };
  ushort_t* ebf  = (ushort_t*)carve((size_t)N * D * 2);       // 25.6 MB
  ushort_t* h    = (ushort_t*)carve((size_t)N * D * 2);       // 25.6 MB (reused as h2)
  ushort_t* hagg = (ushort_t*)carve((size_t)N * K * 2);       // 102.4 MB
  ushort_t* w1t  = (ushort_t*)carve((size_t)D * K * 2);       // 0.5 MB
  ushort_t* wot  = (ushort_t*)carve((size_t)C * K * 2);       // 0.13 MB
  float* invdeg  = (float*)carve((size_t)M * 4);
  int* rowptr    = (int*)carve(((size_t)M + 1) * 4);
  int* cursor    = (int*)carve((size_t)M * 4);
  int* degcnt    = (int*)carve((size_t)M * 4);
  int* eidx      = (int*)carve((size_t)RE * 4);
  int* blocksum  = (int*)carve(1024 * 4);
  ushort_t* h2 = h;   // h dead after pull_rel(layer1)
  (void)n_in; (void)out_size; (void)ws_size;

  // --- CSR build: flat 3-phase parallel scan over R*N degrees ---
  hipMemsetAsync(degcnt, 0, (size_t)M * 4, stream);
  deg_count_k<<<(RE + 255) / 256, 256, 0, stream>>>(dst, RE, E, N, degcnt);
  int nblkScan = (M + 1023) / 1024;     // 196 <= 1024
  scanA_k<<<nblkScan, 1024, 0, stream>>>(degcnt, M, rowptr, blocksum);
  scanB_k<<<1, 1024, 0, stream>>>(blocksum, nblkScan);
  scanC_k<<<nblkScan, 1024, 0, stream>>>(degcnt, M, blocksum, rowptr, cursor, invdeg);
  fill_k<<<(RE + 255) / 256, 256, 0, stream>>>(src, dst, RE, E, N, cursor, eidx);

  // --- prep: embed->bf16, weights -> transposed bf16 ---
  long n4 = (long)N * D / 4;
  f2bf_vec_k<<<(int)((n4 + 255) / 256), 256, 0, stream>>>(embed, ebf, n4);
  wtrans_k<<<(K * D + 255) / 256, 256, 0, stream>>>(w1, w1t, K, D);
  wtrans_k<<<(K * C + 255) / 256, 256, 0, stream>>>(w_out, wot, K, C);

  const int pullBlocks = (N * 64 + 255) / 256;

  // --- layer 0: h = relu(b0 + sum_r agg_r(embed)) ---
  pull_sum_bf_k<<<pullBlocks, 256, 0, stream>>>(ebf, eidx, rowptr, invdeg,
                                                R, N, h, b0);

  // --- layer 1: hagg = concat_r agg_r(h);  h2 = relu(hagg @ w1cat + b1) ---
  pull_rel_bf_k<<<pullBlocks, 256, 0, stream>>>(h, eidx, rowptr, invdeg,
                                                R, N, hagg);
  {
    dim3 grid(D / 128, (N + 127) / 128);
    gemm_mfma_k<4, 1, 1><<<grid, 256, 0, stream>>>(hagg, w1t, (void*)h2, b1, N, K, D);
  }

  // --- layer 2: hagg = concat_r agg_r(h2); out = hagg @ wocat + b_out ---
  pull_rel_bf_k<<<pullBlocks, 256, 0, stream>>>(h2, eidx, rowptr, invdeg,
                                                R, N, hagg);
  {
    dim3 grid(C / 64, (N + 127) / 128);
    gemm_mfma_k<2, 0, 0><<<grid, 256, 0, stream>>>(hagg, wot, (void*)out, b_out, N, K, C);
  }
}

// Round 6
// 620.275 us; speedup vs baseline: 2.4812x; 1.1139x over previous
//
#include <hip/hip_runtime.h>

// RGCN node classification (matmul-first form):
//   layer0: h  = relu(b0 + sum_r agg_r(embed))            [pull-sum from ebf]
//   layer1: t  = h @ vstack-cols(w1)  (N=1024, bf16)      [MFMA GEMM, no bias]
//           h2 = relu(b1 + sum_r agg_r(t[:, r*256:..]))   [fused 4-rel pull]
//   layer2: q  = h2 @ vstack-cols(w_out) (N=256, bf16)    [MFMA GEMM, no bias]
//           out= b_out + sum_r agg_r(q[:, r*64:..])       [64-col pull]
// CSR built per call (flat 3-phase scan). Pulls absorb the 102MB streams
// (gather-structured, high MLP); GEMMs only read 25.6MB L2-resident A.

typedef unsigned short ushort_t;
using f32x4  = __attribute__((ext_vector_type(4))) float;
using short8 = __attribute__((ext_vector_type(8))) short;

__device__ inline float bf2f(unsigned s) { return __uint_as_float(s << 16); }
__device__ inline unsigned short f2bf(float f) {
  unsigned u = __float_as_uint(f);
  u += 0x7FFF + ((u >> 16) & 1);  // round-to-nearest-even
  return (unsigned short)(u >> 16);
}

// ---------------- CSR build ----------------
// grid: (ceil(E/(256*4)), R); 4 edges/thread, int4 loads, 4 atomics in flight.
__global__ void deg_count_k(const int* __restrict__ dst, int E, int Nn,
                            int* __restrict__ degcnt) {
  int g0 = (blockIdx.x * blockDim.x + threadIdx.x) * 4;
  int r = blockIdx.y;
  if (g0 >= E) return;
  int* dc = degcnt + (size_t)r * Nn;
  if (g0 + 3 < E) {
    const int4 d4 = *reinterpret_cast<const int4*>(dst + (size_t)r * E + g0);
    atomicAdd(&dc[d4.x], 1); atomicAdd(&dc[d4.y], 1);
    atomicAdd(&dc[d4.z], 1); atomicAdd(&dc[d4.w], 1);
  } else {
    for (int j = 0; j < 4 && g0 + j < E; j++)
      atomicAdd(&dc[dst[(size_t)r * E + g0 + j]], 1);
  }
}

// Phase A: per-block (1024 elems) exclusive scan of degcnt -> rowptr, block sums.
__global__ __launch_bounds__(1024) void scanA_k(const int* __restrict__ degcnt, int M,
                                                int* __restrict__ rowptr,
                                                int* __restrict__ blocksum) {
  __shared__ int sm[1024];
  int t = threadIdx.x;
  int g = blockIdx.x * 1024 + t;
  int v = (g < M) ? degcnt[g] : 0;
  sm[t] = v;
  __syncthreads();
  for (int off = 1; off < 1024; off <<= 1) {
    int u = (t >= off) ? sm[t - off] : 0;
    __syncthreads();
    sm[t] += u;
    __syncthreads();
  }
  if (g < M) rowptr[g] = sm[t] - v;
  if (t == 1023) blocksum[blockIdx.x] = sm[1023];
}

// Phase B: one block scans the block sums (exclusive, in place). nb <= 1024.
__global__ __launch_bounds__(1024) void scanB_k(int* __restrict__ blocksum, int nb) {
  __shared__ int sm[1024];
  int t = threadIdx.x;
  int v = (t < nb) ? blocksum[t] : 0;
  sm[t] = v;
  __syncthreads();
  for (int off = 1; off < 1024; off <<= 1) {
    int u = (t >= off) ? sm[t - off] : 0;
    __syncthreads();
    sm[t] += u;
    __syncthreads();
  }
  if (t < nb) blocksum[t] = sm[t] - v;
}

// Phase C: add block offset; emit final rowptr, cursor, invdeg.
__global__ __launch_bounds__(1024) void scanC_k(const int* __restrict__ degcnt, int M,
                                                const int* __restrict__ blocksum,
                                                int* __restrict__ rowptr,
                                                int* __restrict__ cursor,
                                                float* __restrict__ invdeg) {
  int g = blockIdx.x * 1024 + threadIdx.x;
  if (g < M) {
    int val = rowptr[g] + blocksum[blockIdx.x];
    int dd = degcnt[g];
    rowptr[g] = val;
    cursor[g] = val;
    invdeg[g] = 1.0f / (float)(dd > 0 ? dd : 1);
    if (g == M - 1) rowptr[M] = val + dd;
  }
}

// grid: (ceil(E/(256*4)), R); 4 edges/thread.
__global__ void fill_k(const int* __restrict__ src, const int* __restrict__ dst,
                       int E, int Nn,
                       int* __restrict__ cursor, int* __restrict__ eidx) {
  int g0 = (blockIdx.x * blockDim.x + threadIdx.x) * 4;
  int r = blockIdx.y;
  if (g0 >= E) return;
  int* cur = cursor + (size_t)r * Nn;
  if (g0 + 3 < E) {
    const int4 d4 = *reinterpret_cast<const int4*>(dst + (size_t)r * E + g0);
    const int4 s4 = *reinterpret_cast<const int4*>(src + (size_t)r * E + g0);
    int p0 = atomicAdd(&cur[d4.x], 1);
    int p1 = atomicAdd(&cur[d4.y], 1);
    int p2 = atomicAdd(&cur[d4.z], 1);
    int p3 = atomicAdd(&cur[d4.w], 1);
    eidx[p0] = s4.x; eidx[p1] = s4.y; eidx[p2] = s4.z; eidx[p3] = s4.w;
  } else {
    for (int j = 0; j < 4 && g0 + j < E; j++) {
      int p = atomicAdd(&cur[dst[(size_t)r * E + g0 + j]], 1);
      eidx[p] = src[(size_t)r * E + g0 + j];
    }
  }
}

// ---------------- prep: f32 -> bf16, weight transpose ----------------
__global__ void f2bf_vec_k(const float* __restrict__ in, ushort_t* __restrict__ out,
                           long n4) {
  long i = (long)blockIdx.x * blockDim.x + threadIdx.x;
  if (i < n4) {
    float4 v = *reinterpret_cast<const float4*>(in + i * 4);
    ushort4 o; o.x = f2bf(v.x); o.y = f2bf(v.y); o.z = f2bf(v.z); o.w = f2bf(v.w);
    *reinterpret_cast<ushort4*>(out + i * 4) = o;
  }
}

// Bt[j][k] = (bf16) w[r][k][c] with j = r*Nd + c.  w: [R][K][Nd] f32,
// Bt: [R*Nd][K] bf16. tid fastest over k -> coalesced Bt writes.
__global__ void wtrans_k(const float* __restrict__ w, ushort_t* __restrict__ wt,
                         int K, int Nd, int total) {
  int tid = blockIdx.x * blockDim.x + threadIdx.x;
  if (tid < total) {
    int k = tid % K;
    int j = tid / K;
    int c = j % Nd;
    int r = j / Nd;
    wt[(size_t)j * K + k] = f2bf(w[((size_t)r * K + k) * Nd + c]);
  }
}

// ---------------- pull, 256-wide slices (wave per node, lane = 4 cols) ----------
// out[node][c] = relu(bias[c] + sum_r invdeg[r][node] * sum_{e in adj_r} x[src_e][r*rsub + c])
__global__ __launch_bounds__(256) void pull_gather256_k(
    const ushort_t* __restrict__ x, int xpitch, int rsub,
    const int* __restrict__ eidx,
    const int* __restrict__ rowptr, const float* __restrict__ invdeg,
    int R, int Nn, ushort_t* __restrict__ out, const float* __restrict__ bias) {
  int wid = (blockIdx.x * blockDim.x + threadIdx.x) >> 6;
  if (wid >= Nn) return;
  int lane = threadIdx.x & 63;
  int col4 = lane << 2;
  const int D = 256;
  const int* ei = eidx;
  float sx = 0.f, sy = 0.f, sz = 0.f, sw = 0.f;
  for (int r = 0; r < R; r++) {
    const int* rp = rowptr + (size_t)r * Nn;   // flat; rp[wid+1] valid at boundary
    int s = rp[wid], e = rp[wid + 1];
    int rbase = r * rsub + col4;
    float px = 0.f, py = 0.f, pz = 0.f, pw = 0.f;
    for (int i = s; i < e; i += 4) {
      int i1 = i + 1 < e ? i + 1 : i;
      int i2 = i + 2 < e ? i + 2 : i;
      int i3 = i + 3 < e ? i + 3 : i;
      float m1 = i + 1 < e ? 1.f : 0.f;
      float m2 = i + 2 < e ? 1.f : 0.f;
      float m3 = i + 3 < e ? 1.f : 0.f;
      int n0 = ei[i], n1 = ei[i1], n2 = ei[i2], n3 = ei[i3];
      const uint2 v0 = *reinterpret_cast<const uint2*>(x + (size_t)n0 * xpitch + rbase);
      const uint2 v1 = *reinterpret_cast<const uint2*>(x + (size_t)n1 * xpitch + rbase);
      const uint2 v2 = *reinterpret_cast<const uint2*>(x + (size_t)n2 * xpitch + rbase);
      const uint2 v3 = *reinterpret_cast<const uint2*>(x + (size_t)n3 * xpitch + rbase);
      px += bf2f(v0.x & 0xffffu) + m1 * bf2f(v1.x & 0xffffu) +
            m2 * bf2f(v2.x & 0xffffu) + m3 * bf2f(v3.x & 0xffffu);
      py += bf2f(v0.x >> 16) + m1 * bf2f(v1.x >> 16) +
            m2 * bf2f(v2.x >> 16) + m3 * bf2f(v3.x >> 16);
      pz += bf2f(v0.y & 0xffffu) + m1 * bf2f(v1.y & 0xffffu) +
            m2 * bf2f(v2.y & 0xffffu) + m3 * bf2f(v3.y & 0xffffu);
      pw += bf2f(v0.y >> 16) + m1 * bf2f(v1.y >> 16) +
            m2 * bf2f(v2.y >> 16) + m3 * bf2f(v3.y >> 16);
    }
    float w = invdeg[(size_t)r * Nn + wid];
    sx += px * w; sy += py * w; sz += pz * w; sw += pw * w;
  }
  const float4 b = *reinterpret_cast<const float4*>(bias + col4);
  sx = fmaxf(sx + b.x, 0.f); sy = fmaxf(sy + b.y, 0.f);
  sz = fmaxf(sz + b.z, 0.f); sw = fmaxf(sw + b.w, 0.f);
  ushort4 o; o.x = f2bf(sx); o.y = f2bf(sy); o.z = f2bf(sz); o.w = f2bf(sw);
  *reinterpret_cast<ushort4*>(out + (size_t)wid * D + col4) = o;
}

// ---------------- output pull, 64 cols (wave per node, 2 edges in parallel) ----
// out[node][c] = bias[c] + sum_r invdeg[r][node]*sum_{e in adj_r} q[src_e][r*64+c]
// lane: half = lane>>5 (edge slot), cp = (lane&31)*2 (col pair). f32 out.
__global__ __launch_bounds__(256) void pull_out64_k(
    const ushort_t* __restrict__ q, int qpitch,
    const int* __restrict__ eidx,
    const int* __restrict__ rowptr, const float* __restrict__ invdeg,
    int R, int Nn, float* __restrict__ out, const float* __restrict__ bias) {
  int wid = (blockIdx.x * blockDim.x + threadIdx.x) >> 6;
  if (wid >= Nn) return;
  int lane = threadIdx.x & 63;
  int half = lane >> 5;
  int cp = (lane & 31) << 1;
  float s0 = 0.f, s1 = 0.f;
  for (int r = 0; r < R; r++) {
    const int* rp = rowptr + (size_t)r * Nn;
    int s = rp[wid], e = rp[wid + 1];
    int rbase = (r << 6) + cp;
    float p0 = 0.f, p1 = 0.f;
    for (int i = s + half; i < e; i += 4) {
      int ib = i + 2 < e ? i + 2 : i;
      float mb = i + 2 < e ? 1.f : 0.f;
      int na = eidx[i], nb = eidx[ib];
      unsigned va = *reinterpret_cast<const unsigned*>(q + (size_t)na * qpitch + rbase);
      unsigned vb = *reinterpret_cast<const unsigned*>(q + (size_t)nb * qpitch + rbase);
      p0 += bf2f(va & 0xffffu) + mb * bf2f(vb & 0xffffu);
      p1 += bf2f(va >> 16) + mb * bf2f(vb >> 16);
    }
    float w = invdeg[(size_t)r * Nn + wid];
    s0 += p0 * w; s1 += p1 * w;
  }
  s0 += __shfl_xor(s0, 32, 64);
  s1 += __shfl_xor(s1, 32, 64);
  if (half == 0) {
    float2 o; o.x = s0 + bias[cp]; o.y = s1 + bias[cp + 1];
    *reinterpret_cast<float2*>(out + (size_t)wid * 64 + cp) = o;
  }
}

// ---------------- bf16 MFMA GEMM (no bias/relu, bf16 store) ----------------
// C[M][Nd] = A[M][K] @ Bt[Nd][K]^T. 256 threads = 4 waves (2x2).
// BM=128, BN=FN*32. A staged in LDS (pitch 72: 2-way bank aliasing = free).
template <int FN>
__global__ __launch_bounds__(256) void gemm_mfma_k(
    const ushort_t* __restrict__ A, const ushort_t* __restrict__ Bt,
    ushort_t* __restrict__ Cp, int M, int K, int Nd) {
  __shared__ ushort_t Atile[128][72];
  const int tid = threadIdx.x;
  const int lane = tid & 63;
  const int wid = tid >> 6;
  const int wr = wid >> 1;
  const int wc = wid & 1;
  const int rowBase = blockIdx.y * 128;
  const int colBase = blockIdx.x * (FN * 32);
  const int l15 = lane & 15;
  const int g = lane >> 4;

  f32x4 acc[4][FN] = {};

  const int srow = tid >> 3;
  const int schunk = tid & 7;

  for (int k0 = 0; k0 < K; k0 += 64) {
#pragma unroll
    for (int i = 0; i < 4; i++) {
      int row = srow + i * 32;
      int grow = rowBase + row;
      if (grow >= M) grow = M - 1;  // clamp: affects only unstored C rows
      short8 v = *reinterpret_cast<const short8*>(A + (size_t)grow * K + k0 + schunk * 8);
      *reinterpret_cast<short8*>(&Atile[row][schunk * 8]) = v;
    }
    __syncthreads();
#pragma unroll
    for (int kk = 0; kk < 2; kk++) {
      short8 a[4], b[FN];
#pragma unroll
      for (int m = 0; m < 4; m++)
        a[m] = *reinterpret_cast<const short8*>(&Atile[wr * 64 + m * 16 + l15][kk * 32 + g * 8]);
#pragma unroll
      for (int n = 0; n < FN; n++) {
        int col = colBase + wc * (FN * 16) + n * 16 + l15;
        b[n] = *reinterpret_cast<const short8*>(Bt + (size_t)col * K + k0 + kk * 32 + g * 8);
      }
#pragma unroll
      for (int m = 0; m < 4; m++)
#pragma unroll
        for (int n = 0; n < FN; n++)
          acc[m][n] = __builtin_amdgcn_mfma_f32_16x16x32_bf16(a[m], b[n], acc[m][n], 0, 0, 0);
    }
    __syncthreads();
  }

  // C/D layout: col=lane&15, row=(lane>>4)*4+reg  [guide §3, m89-verified]
#pragma unroll
  for (int n = 0; n < FN; n++) {
    int col = colBase + wc * (FN * 16) + n * 16 + l15;
#pragma unroll
    for (int m = 0; m < 4; m++) {
      int row0 = rowBase + wr * 64 + m * 16 + g * 4;
#pragma unroll
      for (int j = 0; j < 4; j++) {
        int row = row0 + j;
        if (row < M) Cp[(size_t)row * Nd + col] = f2bf(acc[m][n][j]);
      }
    }
  }
}

extern "C" void kernel_launch(void* const* d_in, const int* in_sizes, int n_in,
                              void* d_out, int out_size, void* d_ws, size_t ws_size,
                              hipStream_t stream) {
  const float* embed = (const float*)d_in[0];
  const int* src     = (const int*)d_in[1];
  const int* dst     = (const int*)d_in[2];
  const float* b0    = (const float*)d_in[3];
  const float* w1    = (const float*)d_in[4];
  const float* b1    = (const float*)d_in[5];
  const float* w_out = (const float*)d_in[6];
  const float* b_out = (const float*)d_in[7];
  float* out = (float*)d_out;

  const int D = in_sizes[3];            // 256
  const int C = in_sizes[7];            // 64
  const int N = in_sizes[0] / D;        // 50000
  const int R = in_sizes[4] / (D * D);  // 4
  const int E = in_sizes[1] / R;        // 400000
  const int M = R * N;                  // scan length
  const int N1 = R * D;                 // 1024 gemm1 out cols
  const int N2 = R * C;                 // 256  gemm2 out cols

  char* w = (char*)d_ws;
  size_t off = 0;
  auto carve = [&](size_t bytes) -> void* {
    void* p = w + off;
    off += (bytes + 255) & ~(size_t)255;
    return p;
  };
  ushort_t* ebf  = (ushort_t*)carve((size_t)N * D * 2);       // 25.6 MB (reused as h2)
  ushort_t* h    = (ushort_t*)carve((size_t)N * D * 2);       // 25.6 MB
  ushort_t* t    = (ushort_t*)carve((size_t)N * N1 * 2);      // 102.4 MB (reused as q)
  ushort_t* w1t  = (ushort_t*)carve((size_t)N1 * D * 2);      // 0.5 MB
  ushort_t* wot  = (ushort_t*)carve((size_t)N2 * D * 2);      // 0.13 MB
  float* invdeg  = (float*)carve((size_t)M * 4);
  int* rowptr    = (int*)carve(((size_t)M + 1) * 4);
  int* cursor    = (int*)carve((size_t)M * 4);
  int* degcnt    = (int*)carve((size_t)M * 4);
  int* eidx      = (int*)carve((size_t)R * E * 4);
  int* blocksum  = (int*)carve(1024 * 4);
  ushort_t* h2 = ebf;   // ebf dead after layer-0 pull
  ushort_t* q  = t;     // t dead after layer-1 pull
  (void)n_in; (void)out_size; (void)ws_size;

  // --- CSR build ---
  hipMemsetAsync(degcnt, 0, (size_t)M * 4, stream);
  dim3 egrid((E + 1023) / 1024, R);
  deg_count_k<<<egrid, 256, 0, stream>>>(dst, E, N, degcnt);
  int nblkScan = (M + 1023) / 1024;     // 196 <= 1024
  scanA_k<<<nblkScan, 1024, 0, stream>>>(degcnt, M, rowptr, blocksum);
  scanB_k<<<1, 1024, 0, stream>>>(blocksum, nblkScan);
  scanC_k<<<nblkScan, 1024, 0, stream>>>(degcnt, M, blocksum, rowptr, cursor, invdeg);
  fill_k<<<egrid, 256, 0, stream>>>(src, dst, E, N, cursor, eidx);

  // --- prep: embed->bf16, weights -> [outcol][k] bf16 ---
  long n4 = (long)N * D / 4;
  f2bf_vec_k<<<(int)((n4 + 255) / 256), 256, 0, stream>>>(embed, ebf, n4);
  wtrans_k<<<(N1 * D + 255) / 256, 256, 0, stream>>>(w1, w1t, D, D, N1 * D);
  wtrans_k<<<(N2 * D + 255) / 256, 256, 0, stream>>>(w_out, wot, D, C, N2 * D);

  const int pullBlocks = (N * 64 + 255) / 256;

  // --- layer 0: h = relu(b0 + sum_r agg_r(embed)) ---
  pull_gather256_k<<<pullBlocks, 256, 0, stream>>>(ebf, D, 0, eidx, rowptr, invdeg,
                                                   R, N, h, b0);

  // --- layer 1: t = h @ w1cat; h2 = relu(b1 + sum_r agg_r(t[:,r*256:])) ---
  {
    dim3 grid(N1 / 128, (N + 127) / 128);
    gemm_mfma_k<4><<<grid, 256, 0, stream>>>(h, w1t, t, N, D, N1);
  }
  pull_gather256_k<<<pullBlocks, 256, 0, stream>>>(t, N1, D, eidx, rowptr, invdeg,
                                                   R, N, h2, b1);

  // --- layer 2: q = h2 @ wocat; out = b_out + sum_r agg_r(q[:,r*64:]) ---
  {
    dim3 grid(N2 / 128, (N + 127) / 128);
    gemm_mfma_k<4><<<grid, 256, 0, stream>>>(h2, wot, q, N, D, N2);
  }
  pull_out64_k<<<pullBlocks, 256, 0, stream>>>(q, N2, eidx, rowptr, invdeg,
                                               R, N, out, b_out);
}

// Round 7
// 527.196 us; speedup vs baseline: 2.9193x; 1.1766x over previous
//
#include <hip/hip_runtime.h>

// RGCN node classification (matmul-first form):
//   layer0: h  = relu(b0 + sum_r agg_r(embed))            [pull-sum from ebf]
//   layer1: t  = h @ vstack-cols(w1)  (N=1024, bf16)      [MFMA GEMM]
//           h2 = relu(b1 + sum_r agg_r(t[:, r*256:..]))   [fused 4-rel pull]
//   layer2: q  = h2 @ vstack-cols(w_out) (N=256, bf16)    [MFMA GEMM]
//           out= b_out + sum_r agg_r(q[:, r*64:..])       [64-col pull]
// CSR built per call via the rank trick: pass1 atomicAdd returns each edge's
// occurrence rank AND leaves degrees in cnt; pass2 scatter is atomic-free.

typedef unsigned short ushort_t;
using f32x4  = __attribute__((ext_vector_type(4))) float;
using short8 = __attribute__((ext_vector_type(8))) short;

__device__ inline float bf2f(unsigned s) { return __uint_as_float(s << 16); }
__device__ inline unsigned short f2bf(float f) {
  unsigned u = __float_as_uint(f);
  u += 0x7FFF + ((u >> 16) & 1);  // round-to-nearest-even
  return (unsigned short)(u >> 16);
}

// ---------------- CSR build ----------------
// Pass 1: rank[g] = atomicAdd(cnt[r][dst[g]], 1). After this, cnt = degrees.
// grid: (ceil(E/(256*8)), R); 8 edges/thread, 8 atomics in flight.
__global__ void rank_k(const int* __restrict__ dst, int E, int Nn,
                       int* __restrict__ cnt, int* __restrict__ rank) {
  int base = (blockIdx.x * blockDim.x + threadIdx.x) * 8;
  int r = blockIdx.y;
  if (base >= E) return;
  const int* dr = dst + (size_t)r * E;
  int* cr = cnt + (size_t)r * Nn;
  int* rk = rank + (size_t)r * E;
  if (base + 7 < E) {
    const int4 a = *reinterpret_cast<const int4*>(dr + base);
    const int4 b = *reinterpret_cast<const int4*>(dr + base + 4);
    int4 ra, rb;
    ra.x = atomicAdd(&cr[a.x], 1); ra.y = atomicAdd(&cr[a.y], 1);
    ra.z = atomicAdd(&cr[a.z], 1); ra.w = atomicAdd(&cr[a.w], 1);
    rb.x = atomicAdd(&cr[b.x], 1); rb.y = atomicAdd(&cr[b.y], 1);
    rb.z = atomicAdd(&cr[b.z], 1); rb.w = atomicAdd(&cr[b.w], 1);
    *reinterpret_cast<int4*>(rk + base) = ra;
    *reinterpret_cast<int4*>(rk + base + 4) = rb;
  } else {
    for (int j = 0; j < 8 && base + j < E; j++)
      rk[base + j] = atomicAdd(&cr[dr[base + j]], 1);
  }
}

// Phase A: per-block (1024 elems) exclusive scan of cnt -> rowptr, block sums.
__global__ __launch_bounds__(1024) void scanA_k(const int* __restrict__ degcnt, int M,
                                                int* __restrict__ rowptr,
                                                int* __restrict__ blocksum) {
  __shared__ int sm[1024];
  int t = threadIdx.x;
  int g = blockIdx.x * 1024 + t;
  int v = (g < M) ? degcnt[g] : 0;
  sm[t] = v;
  __syncthreads();
  for (int off = 1; off < 1024; off <<= 1) {
    int u = (t >= off) ? sm[t - off] : 0;
    __syncthreads();
    sm[t] += u;
    __syncthreads();
  }
  if (g < M) rowptr[g] = sm[t] - v;
  if (t == 1023) blocksum[blockIdx.x] = sm[1023];
}

// Phase B: one block scans the block sums (exclusive, in place). nb <= 1024.
__global__ __launch_bounds__(1024) void scanB_k(int* __restrict__ blocksum, int nb) {
  __shared__ int sm[1024];
  int t = threadIdx.x;
  int v = (t < nb) ? blocksum[t] : 0;
  sm[t] = v;
  __syncthreads();
  for (int off = 1; off < 1024; off <<= 1) {
    int u = (t >= off) ? sm[t - off] : 0;
    __syncthreads();
    sm[t] += u;
    __syncthreads();
  }
  if (t < nb) blocksum[t] = sm[t] - v;
}

// Phase C: add block offset; emit final rowptr and invdeg.
__global__ __launch_bounds__(1024) void scanC_k(const int* __restrict__ degcnt, int M,
                                                const int* __restrict__ blocksum,
                                                int* __restrict__ rowptr,
                                                float* __restrict__ invdeg) {
  int g = blockIdx.x * 1024 + threadIdx.x;
  if (g < M) {
    int val = rowptr[g] + blocksum[blockIdx.x];
    int dd = degcnt[g];
    rowptr[g] = val;
    invdeg[g] = 1.0f / (float)(dd > 0 ? dd : 1);
    if (g == M - 1) rowptr[M] = val + dd;
  }
}

// Pass 2: eidx[rowptr[r][dst] + rank] = src. NO atomics.
// grid: (ceil(E/(256*8)), R); 8 edges/thread.
__global__ void fill_k(const int* __restrict__ src, const int* __restrict__ dst,
                       const int* __restrict__ rank,
                       const int* __restrict__ rowptr, int E, int Nn,
                       int* __restrict__ eidx) {
  int base = (blockIdx.x * blockDim.x + threadIdx.x) * 8;
  int r = blockIdx.y;
  if (base >= E) return;
  const int* dr = dst + (size_t)r * E;
  const int* sr = src + (size_t)r * E;
  const int* rk = rank + (size_t)r * E;
  const int* rp = rowptr + (size_t)r * Nn;
  if (base + 7 < E) {
    const int4 d0 = *reinterpret_cast<const int4*>(dr + base);
    const int4 d1 = *reinterpret_cast<const int4*>(dr + base + 4);
    const int4 s0 = *reinterpret_cast<const int4*>(sr + base);
    const int4 s1 = *reinterpret_cast<const int4*>(sr + base + 4);
    const int4 k0 = *reinterpret_cast<const int4*>(rk + base);
    const int4 k1 = *reinterpret_cast<const int4*>(rk + base + 4);
    eidx[rp[d0.x] + k0.x] = s0.x;
    eidx[rp[d0.y] + k0.y] = s0.y;
    eidx[rp[d0.z] + k0.z] = s0.z;
    eidx[rp[d0.w] + k0.w] = s0.w;
    eidx[rp[d1.x] + k1.x] = s1.x;
    eidx[rp[d1.y] + k1.y] = s1.y;
    eidx[rp[d1.z] + k1.z] = s1.z;
    eidx[rp[d1.w] + k1.w] = s1.w;
  } else {
    for (int j = 0; j < 8 && base + j < E; j++)
      eidx[rp[dr[base + j]] + rk[base + j]] = sr[base + j];
  }
}

// ---------------- prep: f32 -> bf16, weight transpose ----------------
__global__ void f2bf_vec_k(const float* __restrict__ in, ushort_t* __restrict__ out,
                           long n4) {
  long i = (long)blockIdx.x * blockDim.x + threadIdx.x;
  if (i < n4) {
    float4 v = *reinterpret_cast<const float4*>(in + i * 4);
    ushort4 o; o.x = f2bf(v.x); o.y = f2bf(v.y); o.z = f2bf(v.z); o.w = f2bf(v.w);
    *reinterpret_cast<ushort4*>(out + i * 4) = o;
  }
}

// Bt[j][k] = (bf16) w[r][k][c] with j = r*Nd + c.  w: [R][K][Nd] f32,
// Bt: [R*Nd][K] bf16. tid fastest over k -> coalesced Bt writes.
__global__ void wtrans_k(const float* __restrict__ w, ushort_t* __restrict__ wt,
                         int K, int Nd, int total) {
  int tid = blockIdx.x * blockDim.x + threadIdx.x;
  if (tid < total) {
    int k = tid % K;
    int j = tid / K;
    int c = j % Nd;
    int r = j / Nd;
    wt[(size_t)j * K + k] = f2bf(w[((size_t)r * K + k) * Nd + c]);
  }
}

// ---------------- pull, 256-wide slices (wave per node, lane = 4 cols) ----------
__global__ __launch_bounds__(256) void pull_gather256_k(
    const ushort_t* __restrict__ x, int xpitch, int rsub,
    const int* __restrict__ eidx,
    const int* __restrict__ rowptr, const float* __restrict__ invdeg,
    int R, int Nn, ushort_t* __restrict__ out, const float* __restrict__ bias) {
  int wid = (blockIdx.x * blockDim.x + threadIdx.x) >> 6;
  if (wid >= Nn) return;
  int lane = threadIdx.x & 63;
  int col4 = lane << 2;
  const int D = 256;
  const int* ei = eidx;
  float sx = 0.f, sy = 0.f, sz = 0.f, sw = 0.f;
  for (int r = 0; r < R; r++) {
    const int* rp = rowptr + (size_t)r * Nn;   // flat; rp[wid+1] valid at boundary
    int s = rp[wid], e = rp[wid + 1];
    int rbase = r * rsub + col4;
    float px = 0.f, py = 0.f, pz = 0.f, pw = 0.f;
    for (int i = s; i < e; i += 4) {
      int i1 = i + 1 < e ? i + 1 : i;
      int i2 = i + 2 < e ? i + 2 : i;
      int i3 = i + 3 < e ? i + 3 : i;
      float m1 = i + 1 < e ? 1.f : 0.f;
      float m2 = i + 2 < e ? 1.f : 0.f;
      float m3 = i + 3 < e ? 1.f : 0.f;
      int n0 = ei[i], n1 = ei[i1], n2 = ei[i2], n3 = ei[i3];
      const uint2 v0 = *reinterpret_cast<const uint2*>(x + (size_t)n0 * xpitch + rbase);
      const uint2 v1 = *reinterpret_cast<const uint2*>(x + (size_t)n1 * xpitch + rbase);
      const uint2 v2 = *reinterpret_cast<const uint2*>(x + (size_t)n2 * xpitch + rbase);
      const uint2 v3 = *reinterpret_cast<const uint2*>(x + (size_t)n3 * xpitch + rbase);
      px += bf2f(v0.x & 0xffffu) + m1 * bf2f(v1.x & 0xffffu) +
            m2 * bf2f(v2.x & 0xffffu) + m3 * bf2f(v3.x & 0xffffu);
      py += bf2f(v0.x >> 16) + m1 * bf2f(v1.x >> 16) +
            m2 * bf2f(v2.x >> 16) + m3 * bf2f(v3.x >> 16);
      pz += bf2f(v0.y & 0xffffu) + m1 * bf2f(v1.y & 0xffffu) +
            m2 * bf2f(v2.y & 0xffffu) + m3 * bf2f(v3.y & 0xffffu);
      pw += bf2f(v0.y >> 16) + m1 * bf2f(v1.y >> 16) +
            m2 * bf2f(v2.y >> 16) + m3 * bf2f(v3.y >> 16);
    }
    float w = invdeg[(size_t)r * Nn + wid];
    sx += px * w; sy += py * w; sz += pz * w; sw += pw * w;
  }
  const float4 b = *reinterpret_cast<const float4*>(bias + col4);
  sx = fmaxf(sx + b.x, 0.f); sy = fmaxf(sy + b.y, 0.f);
  sz = fmaxf(sz + b.z, 0.f); sw = fmaxf(sw + b.w, 0.f);
  ushort4 o; o.x = f2bf(sx); o.y = f2bf(sy); o.z = f2bf(sz); o.w = f2bf(sw);
  *reinterpret_cast<ushort4*>(out + (size_t)wid * D + col4) = o;
}

// ---------------- output pull, 64 cols (wave per node, 2 edges in parallel) ----
__global__ __launch_bounds__(256) void pull_out64_k(
    const ushort_t* __restrict__ q, int qpitch,
    const int* __restrict__ eidx,
    const int* __restrict__ rowptr, const float* __restrict__ invdeg,
    int R, int Nn, float* __restrict__ out, const float* __restrict__ bias) {
  int wid = (blockIdx.x * blockDim.x + threadIdx.x) >> 6;
  if (wid >= Nn) return;
  int lane = threadIdx.x & 63;
  int half = lane >> 5;
  int cp = (lane & 31) << 1;
  float s0 = 0.f, s1 = 0.f;
  for (int r = 0; r < R; r++) {
    const int* rp = rowptr + (size_t)r * Nn;
    int s = rp[wid], e = rp[wid + 1];
    int rbase = (r << 6) + cp;
    float p0 = 0.f, p1 = 0.f;
    for (int i = s + half; i < e; i += 4) {
      int ib = i + 2 < e ? i + 2 : i;
      float mb = i + 2 < e ? 1.f : 0.f;
      int na = eidx[i], nb = eidx[ib];
      unsigned va = *reinterpret_cast<const unsigned*>(q + (size_t)na * qpitch + rbase);
      unsigned vb = *reinterpret_cast<const unsigned*>(q + (size_t)nb * qpitch + rbase);
      p0 += bf2f(va & 0xffffu) + mb * bf2f(vb & 0xffffu);
      p1 += bf2f(va >> 16) + mb * bf2f(vb >> 16);
    }
    float w = invdeg[(size_t)r * Nn + wid];
    s0 += p0 * w; s1 += p1 * w;
  }
  s0 += __shfl_xor(s0, 32, 64);
  s1 += __shfl_xor(s1, 32, 64);
  if (half == 0) {
    float2 o; o.x = s0 + bias[cp]; o.y = s1 + bias[cp + 1];
    *reinterpret_cast<float2*>(out + (size_t)wid * 64 + cp) = o;
  }
}

// ---------------- bf16 MFMA GEMM (no bias/relu, bf16 store) ----------------
template <int FN>
__global__ __launch_bounds__(256) void gemm_mfma_k(
    const ushort_t* __restrict__ A, const ushort_t* __restrict__ Bt,
    ushort_t* __restrict__ Cp, int M, int K, int Nd) {
  __shared__ ushort_t Atile[128][72];
  const int tid = threadIdx.x;
  const int lane = tid & 63;
  const int wid = tid >> 6;
  const int wr = wid >> 1;
  const int wc = wid & 1;
  const int rowBase = blockIdx.y * 128;
  const int colBase = blockIdx.x * (FN * 32);
  const int l15 = lane & 15;
  const int g = lane >> 4;

  f32x4 acc[4][FN] = {};

  const int srow = tid >> 3;
  const int schunk = tid & 7;

  for (int k0 = 0; k0 < K; k0 += 64) {
#pragma unroll
    for (int i = 0; i < 4; i++) {
      int row = srow + i * 32;
      int grow = rowBase + row;
      if (grow >= M) grow = M - 1;  // clamp: affects only unstored C rows
      short8 v = *reinterpret_cast<const short8*>(A + (size_t)grow * K + k0 + schunk * 8);
      *reinterpret_cast<short8*>(&Atile[row][schunk * 8]) = v;
    }
    __syncthreads();
#pragma unroll
    for (int kk = 0; kk < 2; kk++) {
      short8 a[4], b[FN];
#pragma unroll
      for (int m = 0; m < 4; m++)
        a[m] = *reinterpret_cast<const short8*>(&Atile[wr * 64 + m * 16 + l15][kk * 32 + g * 8]);
#pragma unroll
      for (int n = 0; n < FN; n++) {
        int col = colBase + wc * (FN * 16) + n * 16 + l15;
        b[n] = *reinterpret_cast<const short8*>(Bt + (size_t)col * K + k0 + kk * 32 + g * 8);
      }
#pragma unroll
      for (int m = 0; m < 4; m++)
#pragma unroll
        for (int n = 0; n < FN; n++)
          acc[m][n] = __builtin_amdgcn_mfma_f32_16x16x32_bf16(a[m], b[n], acc[m][n], 0, 0, 0);
    }
    __syncthreads();
  }

  // C/D layout: col=lane&15, row=(lane>>4)*4+reg  [guide §3, m89-verified]
#pragma unroll
  for (int n = 0; n < FN; n++) {
    int col = colBase + wc * (FN * 16) + n * 16 + l15;
#pragma unroll
    for (int m = 0; m < 4; m++) {
      int row0 = rowBase + wr * 64 + m * 16 + g * 4;
#pragma unroll
      for (int j = 0; j < 4; j++) {
        int row = row0 + j;
        if (row < M) Cp[(size_t)row * Nd + col] = f2bf(acc[m][n][j]);
      }
    }
  }
}

extern "C" void kernel_launch(void* const* d_in, const int* in_sizes, int n_in,
                              void* d_out, int out_size, void* d_ws, size_t ws_size,
                              hipStream_t stream) {
  const float* embed = (const float*)d_in[0];
  const int* src     = (const int*)d_in[1];
  const int* dst     = (const int*)d_in[2];
  const float* b0    = (const float*)d_in[3];
  const float* w1    = (const float*)d_in[4];
  const float* b1    = (const float*)d_in[5];
  const float* w_out = (const float*)d_in[6];
  const float* b_out = (const float*)d_in[7];
  float* out = (float*)d_out;

  const int D = in_sizes[3];            // 256
  const int C = in_sizes[7];            // 64
  const int N = in_sizes[0] / D;        // 50000
  const int R = in_sizes[4] / (D * D);  // 4
  const int E = in_sizes[1] / R;        // 400000
  const int M = R * N;                  // scan length
  const int N1 = R * D;                 // 1024 gemm1 out cols
  const int N2 = R * C;                 // 256  gemm2 out cols

  char* w = (char*)d_ws;
  size_t off = 0;
  auto carve = [&](size_t bytes) -> void* {
    void* p = w + off;
    off += (bytes + 255) & ~(size_t)255;
    return p;
  };
  ushort_t* ebf  = (ushort_t*)carve((size_t)N * D * 2);       // 25.6 MB (reused as h2)
  ushort_t* h    = (ushort_t*)carve((size_t)N * D * 2);       // 25.6 MB
  ushort_t* t    = (ushort_t*)carve((size_t)N * N1 * 2);      // 102.4 MB (reused as q; rank aliases head)
  ushort_t* w1t  = (ushort_t*)carve((size_t)N1 * D * 2);      // 0.5 MB
  ushort_t* wot  = (ushort_t*)carve((size_t)N2 * D * 2);      // 0.13 MB
  float* invdeg  = (float*)carve((size_t)M * 4);
  int* rowptr    = (int*)carve(((size_t)M + 1) * 4);
  int* degcnt    = (int*)carve((size_t)M * 4);
  int* eidx      = (int*)carve((size_t)R * E * 4);
  int* blocksum  = (int*)carve(1024 * 4);
  ushort_t* h2 = ebf;   // ebf dead after layer-0 pull
  ushort_t* q  = t;     // t dead after layer-1 pull
  int* rank = (int*)t;  // t-space unused until gemm1; rank dead after fill_k
  (void)n_in; (void)out_size; (void)ws_size;

  // --- CSR build: rank pass (atomic, leaves degrees) -> scan -> atomic-free fill ---
  hipMemsetAsync(degcnt, 0, (size_t)M * 4, stream);
  dim3 egrid((E + 2047) / 2048, R);
  rank_k<<<egrid, 256, 0, stream>>>(dst, E, N, degcnt, rank);
  int nblkScan = (M + 1023) / 1024;     // 196 <= 1024
  scanA_k<<<nblkScan, 1024, 0, stream>>>(degcnt, M, rowptr, blocksum);
  scanB_k<<<1, 1024, 0, stream>>>(blocksum, nblkScan);
  scanC_k<<<nblkScan, 1024, 0, stream>>>(degcnt, M, blocksum, rowptr, invdeg);
  fill_k<<<egrid, 256, 0, stream>>>(src, dst, rank, rowptr, E, N, eidx);

  // --- prep: embed->bf16, weights -> [outcol][k] bf16 ---
  long n4 = (long)N * D / 4;
  f2bf_vec_k<<<(int)((n4 + 255) / 256), 256, 0, stream>>>(embed, ebf, n4);
  wtrans_k<<<(N1 * D + 255) / 256, 256, 0, stream>>>(w1, w1t, D, D, N1 * D);
  wtrans_k<<<(N2 * D + 255) / 256, 256, 0, stream>>>(w_out, wot, D, C, N2 * D);

  const int pullBlocks = (N * 64 + 255) / 256;

  // --- layer 0: h = relu(b0 + sum_r agg_r(embed)) ---
  pull_gather256_k<<<pullBlocks, 256, 0, stream>>>(ebf, D, 0, eidx, rowptr, invdeg,
                                                   R, N, h, b0);

  // --- layer 1: t = h @ w1cat; h2 = relu(b1 + sum_r agg_r(t[:,r*256:])) ---
  {
    dim3 grid(N1 / 128, (N + 127) / 128);
    gemm_mfma_k<4><<<grid, 256, 0, stream>>>(h, w1t, t, N, D, N1);
  }
  pull_gather256_k<<<pullBlocks, 256, 0, stream>>>(t, N1, D, eidx, rowptr, invdeg,
                                                   R, N, h2, b1);

  // --- layer 2: q = h2 @ wocat; out = b_out + sum_r agg_r(q[:,r*64:]) ---
  {
    dim3 grid(N2 / 128, (N + 127) / 128);
    gemm_mfma_k<4><<<grid, 256, 0, stream>>>(h2, wot, q, N, D, N2);
  }
  pull_out64_k<<<pullBlocks, 256, 0, stream>>>(q, N2, eidx, rowptr, invdeg,
                                               R, N, out, b_out);
}

// Round 8
// 519.837 us; speedup vs baseline: 2.9606x; 1.0142x over previous
//
#include <hip/hip_runtime.h>

// RGCN node classification (matmul-first form):
//   layer0: h  = relu(b0 + sum_r agg_r(embed))            [pull, 2 nodes/wave]
//   layer1: t  = h @ vstack-cols(w1)  (N=1024, bf16)      [MFMA GEMM]
//           h2 = relu(b1 + sum_r agg_r(t[:, r*256:..]))   [pull, 2 nodes/wave]
//   layer2: q  = h2 @ vstack-cols(w_out) (N=256, bf16)    [MFMA GEMM]
//           out= b_out + sum_r agg_r(q[:, r*64:..])       [pull, 4 edge slots]
// CSR per call via rank trick (pass1 atomicAdd returns rank + leaves degrees;
// pass2 scatter atomic-free). Pulls use wide per-lane loads (uint4/uint2) to
// minimize VMEM instruction count and address math.

typedef unsigned short ushort_t;
using f32x4  = __attribute__((ext_vector_type(4))) float;
using short8 = __attribute__((ext_vector_type(8))) short;

__device__ inline float bf2f(unsigned s) { return __uint_as_float(s << 16); }
__device__ inline unsigned short f2bf(float f) {
  unsigned u = __float_as_uint(f);
  u += 0x7FFF + ((u >> 16) & 1);  // round-to-nearest-even
  return (unsigned short)(u >> 16);
}
__device__ inline void u4tof8(const uint4 v, float f[8]) {
  f[0] = bf2f(v.x & 0xffffu); f[1] = bf2f(v.x >> 16);
  f[2] = bf2f(v.y & 0xffffu); f[3] = bf2f(v.y >> 16);
  f[4] = bf2f(v.z & 0xffffu); f[5] = bf2f(v.z >> 16);
  f[6] = bf2f(v.w & 0xffffu); f[7] = bf2f(v.w >> 16);
}

// ---------------- CSR build ----------------
// Pass 1: rank[g] = atomicAdd(cnt[r][dst[g]], 1). After this, cnt = degrees.
__global__ void rank_k(const int* __restrict__ dst, int E, int Nn,
                       int* __restrict__ cnt, int* __restrict__ rank) {
  int base = (blockIdx.x * blockDim.x + threadIdx.x) * 8;
  int r = blockIdx.y;
  if (base >= E) return;
  const int* dr = dst + (size_t)r * E;
  int* cr = cnt + (size_t)r * Nn;
  int* rk = rank + (size_t)r * E;
  if (base + 7 < E) {
    const int4 a = *reinterpret_cast<const int4*>(dr + base);
    const int4 b = *reinterpret_cast<const int4*>(dr + base + 4);
    int4 ra, rb;
    ra.x = atomicAdd(&cr[a.x], 1); ra.y = atomicAdd(&cr[a.y], 1);
    ra.z = atomicAdd(&cr[a.z], 1); ra.w = atomicAdd(&cr[a.w], 1);
    rb.x = atomicAdd(&cr[b.x], 1); rb.y = atomicAdd(&cr[b.y], 1);
    rb.z = atomicAdd(&cr[b.z], 1); rb.w = atomicAdd(&cr[b.w], 1);
    *reinterpret_cast<int4*>(rk + base) = ra;
    *reinterpret_cast<int4*>(rk + base + 4) = rb;
  } else {
    for (int j = 0; j < 8 && base + j < E; j++)
      rk[base + j] = atomicAdd(&cr[dr[base + j]], 1);
  }
}

// Phase A: per-block (1024 elems) exclusive scan of cnt -> rowptr, block sums.
__global__ __launch_bounds__(1024) void scanA_k(const int* __restrict__ degcnt, int M,
                                                int* __restrict__ rowptr,
                                                int* __restrict__ blocksum) {
  __shared__ int sm[1024];
  int t = threadIdx.x;
  int g = blockIdx.x * 1024 + t;
  int v = (g < M) ? degcnt[g] : 0;
  sm[t] = v;
  __syncthreads();
  for (int off = 1; off < 1024; off <<= 1) {
    int u = (t >= off) ? sm[t - off] : 0;
    __syncthreads();
    sm[t] += u;
    __syncthreads();
  }
  if (g < M) rowptr[g] = sm[t] - v;
  if (t == 1023) blocksum[blockIdx.x] = sm[1023];
}

// Phase B: one block scans the block sums (exclusive, in place). nb <= 1024.
__global__ __launch_bounds__(1024) void scanB_k(int* __restrict__ blocksum, int nb) {
  __shared__ int sm[1024];
  int t = threadIdx.x;
  int v = (t < nb) ? blocksum[t] : 0;
  sm[t] = v;
  __syncthreads();
  for (int off = 1; off < 1024; off <<= 1) {
    int u = (t >= off) ? sm[t - off] : 0;
    __syncthreads();
    sm[t] += u;
    __syncthreads();
  }
  if (t < nb) blocksum[t] = sm[t] - v;
}

// Phase C: add block offset; emit final rowptr and invdeg.
__global__ __launch_bounds__(1024) void scanC_k(const int* __restrict__ degcnt, int M,
                                                const int* __restrict__ blocksum,
                                                int* __restrict__ rowptr,
                                                float* __restrict__ invdeg) {
  int g = blockIdx.x * 1024 + threadIdx.x;
  if (g < M) {
    int val = rowptr[g] + blocksum[blockIdx.x];
    int dd = degcnt[g];
    rowptr[g] = val;
    invdeg[g] = 1.0f / (float)(dd > 0 ? dd : 1);
    if (g == M - 1) rowptr[M] = val + dd;
  }
}

// Pass 2: eidx[rowptr[r][dst] + rank] = src. NO atomics.
__global__ void fill_k(const int* __restrict__ src, const int* __restrict__ dst,
                       const int* __restrict__ rank,
                       const int* __restrict__ rowptr, int E, int Nn,
                       int* __restrict__ eidx) {
  int base = (blockIdx.x * blockDim.x + threadIdx.x) * 8;
  int r = blockIdx.y;
  if (base >= E) return;
  const int* dr = dst + (size_t)r * E;
  const int* sr = src + (size_t)r * E;
  const int* rk = rank + (size_t)r * E;
  const int* rp = rowptr + (size_t)r * Nn;
  if (base + 7 < E) {
    const int4 d0 = *reinterpret_cast<const int4*>(dr + base);
    const int4 d1 = *reinterpret_cast<const int4*>(dr + base + 4);
    const int4 s0 = *reinterpret_cast<const int4*>(sr + base);
    const int4 s1 = *reinterpret_cast<const int4*>(sr + base + 4);
    const int4 k0 = *reinterpret_cast<const int4*>(rk + base);
    const int4 k1 = *reinterpret_cast<const int4*>(rk + base + 4);
    eidx[rp[d0.x] + k0.x] = s0.x;
    eidx[rp[d0.y] + k0.y] = s0.y;
    eidx[rp[d0.z] + k0.z] = s0.z;
    eidx[rp[d0.w] + k0.w] = s0.w;
    eidx[rp[d1.x] + k1.x] = s1.x;
    eidx[rp[d1.y] + k1.y] = s1.y;
    eidx[rp[d1.z] + k1.z] = s1.z;
    eidx[rp[d1.w] + k1.w] = s1.w;
  } else {
    for (int j = 0; j < 8 && base + j < E; j++)
      eidx[rp[dr[base + j]] + rk[base + j]] = sr[base + j];
  }
}

// ---------------- prep: f32 -> bf16, weight transpose ----------------
__global__ void f2bf_vec_k(const float* __restrict__ in, ushort_t* __restrict__ out,
                           long n4) {
  long i = (long)blockIdx.x * blockDim.x + threadIdx.x;
  if (i < n4) {
    float4 v = *reinterpret_cast<const float4*>(in + i * 4);
    ushort4 o; o.x = f2bf(v.x); o.y = f2bf(v.y); o.z = f2bf(v.z); o.w = f2bf(v.w);
    *reinterpret_cast<ushort4*>(out + i * 4) = o;
  }
}

// Bt[j][k] = (bf16) w[r][k][c] with j = r*Nd + c.
__global__ void wtrans_k(const float* __restrict__ w, ushort_t* __restrict__ wt,
                         int K, int Nd, int total) {
  int tid = blockIdx.x * blockDim.x + threadIdx.x;
  if (tid < total) {
    int k = tid % K;
    int j = tid / K;
    int c = j % Nd;
    int r = j / Nd;
    wt[(size_t)j * K + k] = f2bf(w[((size_t)r * K + k) * Nd + c]);
  }
}

// ---------------- pull, 256 cols: 2 nodes/wave, 32 lanes x uint4 (16B) -------
// out[node][c] = relu(bias[c] + sum_r invdeg[r][node]*sum_{e in adj_r} x[src][r*rsub+c])
__global__ __launch_bounds__(256) void pull_gather256_k(
    const ushort_t* __restrict__ x, int xpitch, int rsub,
    const int* __restrict__ eidx,
    const int* __restrict__ rowptr, const float* __restrict__ invdeg,
    int R, int Nn, ushort_t* __restrict__ out, const float* __restrict__ bias) {
  int wv = (blockIdx.x * blockDim.x + threadIdx.x) >> 6;
  int lane = threadIdx.x & 63;
  int node = (wv << 1) + (lane >> 5);
  if (node >= Nn) return;
  int col8 = (lane & 31) << 3;
  float s[8] = {};
  for (int r = 0; r < R; r++) {
    const int* rp = rowptr + (size_t)r * Nn;   // flat; rp[node+1] valid at boundary
    int sb = rp[node], e = rp[node + 1];
    size_t rb = (size_t)(r * rsub + col8);
    float p[8] = {};
    for (int i = sb; i < e; i += 4) {
      int i1 = i + 1 < e ? i + 1 : i;
      int i2 = i + 2 < e ? i + 2 : i;
      int i3 = i + 3 < e ? i + 3 : i;
      float m1 = i + 1 < e ? 1.f : 0.f;
      float m2 = i + 2 < e ? 1.f : 0.f;
      float m3 = i + 3 < e ? 1.f : 0.f;
      const uint4 v0 = *reinterpret_cast<const uint4*>(x + (size_t)eidx[i]  * xpitch + rb);
      const uint4 v1 = *reinterpret_cast<const uint4*>(x + (size_t)eidx[i1] * xpitch + rb);
      const uint4 v2 = *reinterpret_cast<const uint4*>(x + (size_t)eidx[i2] * xpitch + rb);
      const uint4 v3 = *reinterpret_cast<const uint4*>(x + (size_t)eidx[i3] * xpitch + rb);
      float a0[8], a1[8], a2[8], a3[8];
      u4tof8(v0, a0); u4tof8(v1, a1); u4tof8(v2, a2); u4tof8(v3, a3);
#pragma unroll
      for (int j = 0; j < 8; j++)
        p[j] += (a0[j] + m1 * a1[j]) + (m2 * a2[j] + m3 * a3[j]);
    }
    float w = invdeg[(size_t)r * Nn + node];
#pragma unroll
    for (int j = 0; j < 8; j++) s[j] += p[j] * w;
  }
  const float4 ba = *reinterpret_cast<const float4*>(bias + col8);
  const float4 bb = *reinterpret_cast<const float4*>(bias + col8 + 4);
  s[0] += ba.x; s[1] += ba.y; s[2] += ba.z; s[3] += ba.w;
  s[4] += bb.x; s[5] += bb.y; s[6] += bb.z; s[7] += bb.w;
  short8 ov;
#pragma unroll
  for (int j = 0; j < 8; j++) ov[j] = (short)f2bf(fmaxf(s[j], 0.f));
  *reinterpret_cast<short8*>(out + ((size_t)node << 8) + col8) = ov;
}

// ---------------- output pull, 64 cols: 4 edge slots x 16 lanes x uint2 ------
__global__ __launch_bounds__(256) void pull_out64_k(
    const ushort_t* __restrict__ q, int qpitch,
    const int* __restrict__ eidx,
    const int* __restrict__ rowptr, const float* __restrict__ invdeg,
    int R, int Nn, float* __restrict__ out, const float* __restrict__ bias) {
  int node = (blockIdx.x * blockDim.x + threadIdx.x) >> 6;
  if (node >= Nn) return;
  int lane = threadIdx.x & 63;
  int es = lane >> 4;           // edge slot 0..3
  int c4 = (lane & 15) << 2;    // 4 cols per lane (uint2 = 4 bf16)
  float s[4] = {};
  for (int r = 0; r < R; r++) {
    const int* rp = rowptr + (size_t)r * Nn;
    int sb = rp[node], e = rp[node + 1];
    size_t rb = (size_t)((r << 6) + c4);
    float p[4] = {};
    for (int i = sb + es; i < e; i += 4) {
      const uint2 v = *reinterpret_cast<const uint2*>(q + (size_t)eidx[i] * qpitch + rb);
      p[0] += bf2f(v.x & 0xffffu); p[1] += bf2f(v.x >> 16);
      p[2] += bf2f(v.y & 0xffffu); p[3] += bf2f(v.y >> 16);
    }
    float w = invdeg[(size_t)r * Nn + node];
#pragma unroll
    for (int j = 0; j < 4; j++) s[j] += p[j] * w;
  }
#pragma unroll
  for (int j = 0; j < 4; j++) {
    s[j] += __shfl_xor(s[j], 16, 64);
    s[j] += __shfl_xor(s[j], 32, 64);
  }
  if (es == 0) {
    const float4 bv = *reinterpret_cast<const float4*>(bias + c4);
    float4 o;
    o.x = s[0] + bv.x; o.y = s[1] + bv.y; o.z = s[2] + bv.z; o.w = s[3] + bv.w;
    *reinterpret_cast<float4*>(out + ((size_t)node << 6) + c4) = o;
  }
}

// ---------------- bf16 MFMA GEMM (no bias/relu, bf16 store) ----------------
template <int FN>
__global__ __launch_bounds__(256) void gemm_mfma_k(
    const ushort_t* __restrict__ A, const ushort_t* __restrict__ Bt,
    ushort_t* __restrict__ Cp, int M, int K, int Nd) {
  __shared__ ushort_t Atile[128][72];
  const int tid = threadIdx.x;
  const int lane = tid & 63;
  const int wid = tid >> 6;
  const int wr = wid >> 1;
  const int wc = wid & 1;
  const int rowBase = blockIdx.y * 128;
  const int colBase = blockIdx.x * (FN * 32);
  const int l15 = lane & 15;
  const int g = lane >> 4;

  f32x4 acc[4][FN] = {};

  const int srow = tid >> 3;
  const int schunk = tid & 7;

  for (int k0 = 0; k0 < K; k0 += 64) {
#pragma unroll
    for (int i = 0; i < 4; i++) {
      int row = srow + i * 32;
      int grow = rowBase + row;
      if (grow >= M) grow = M - 1;  // clamp: affects only unstored C rows
      short8 v = *reinterpret_cast<const short8*>(A + (size_t)grow * K + k0 + schunk * 8);
      *reinterpret_cast<short8*>(&Atile[row][schunk * 8]) = v;
    }
    __syncthreads();
#pragma unroll
    for (int kk = 0; kk < 2; kk++) {
      short8 a[4], b[FN];
#pragma unroll
      for (int m = 0; m < 4; m++)
        a[m] = *reinterpret_cast<const short8*>(&Atile[wr * 64 + m * 16 + l15][kk * 32 + g * 8]);
#pragma unroll
      for (int n = 0; n < FN; n++) {
        int col = colBase + wc * (FN * 16) + n * 16 + l15;
        b[n] = *reinterpret_cast<const short8*>(Bt + (size_t)col * K + k0 + kk * 32 + g * 8);
      }
#pragma unroll
      for (int m = 0; m < 4; m++)
#pragma unroll
        for (int n = 0; n < FN; n++)
          acc[m][n] = __builtin_amdgcn_mfma_f32_16x16x32_bf16(a[m], b[n], acc[m][n], 0, 0, 0);
    }
    __syncthreads();
  }

  // C/D layout: col=lane&15, row=(lane>>4)*4+reg  [guide §3, m89-verified]
#pragma unroll
  for (int n = 0; n < FN; n++) {
    int col = colBase + wc * (FN * 16) + n * 16 + l15;
#pragma unroll
    for (int m = 0; m < 4; m++) {
      int row0 = rowBase + wr * 64 + m * 16 + g * 4;
#pragma unroll
      for (int j = 0; j < 4; j++) {
        int row = row0 + j;
        if (row < M) Cp[(size_t)row * Nd + col] = f2bf(acc[m][n][j]);
      }
    }
  }
}

extern "C" void kernel_launch(void* const* d_in, const int* in_sizes, int n_in,
                              void* d_out, int out_size, void* d_ws, size_t ws_size,
                              hipStream_t stream) {
  const float* embed = (const float*)d_in[0];
  const int* src     = (const int*)d_in[1];
  const int* dst     = (const int*)d_in[2];
  const float* b0    = (const float*)d_in[3];
  const float* w1    = (const float*)d_in[4];
  const float* b1    = (const float*)d_in[5];
  const float* w_out = (const float*)d_in[6];
  const float* b_out = (const float*)d_in[7];
  float* out = (float*)d_out;

  const int D = in_sizes[3];            // 256
  const int C = in_sizes[7];            // 64
  const int N = in_sizes[0] / D;        // 50000
  const int R = in_sizes[4] / (D * D);  // 4
  const int E = in_sizes[1] / R;        // 400000
  const int M = R * N;                  // scan length
  const int N1 = R * D;                 // 1024 gemm1 out cols
  const int N2 = R * C;                 // 256  gemm2 out cols

  char* w = (char*)d_ws;
  size_t off = 0;
  auto carve = [&](size_t bytes) -> void* {
    void* p = w + off;
    off += (bytes + 255) & ~(size_t)255;
    return p;
  };
  ushort_t* ebf  = (ushort_t*)carve((size_t)N * D * 2);       // 25.6 MB (reused as h2)
  ushort_t* h    = (ushort_t*)carve((size_t)N * D * 2);       // 25.6 MB
  ushort_t* t    = (ushort_t*)carve((size_t)N * N1 * 2);      // 102.4 MB (reused as q; rank aliases head)
  ushort_t* w1t  = (ushort_t*)carve((size_t)N1 * D * 2);      // 0.5 MB
  ushort_t* wot  = (ushort_t*)carve((size_t)N2 * D * 2);      // 0.13 MB
  float* invdeg  = (float*)carve((size_t)M * 4);
  int* rowptr    = (int*)carve(((size_t)M + 1) * 4);
  int* degcnt    = (int*)carve((size_t)M * 4);
  int* eidx      = (int*)carve((size_t)R * E * 4);
  int* blocksum  = (int*)carve(1024 * 4);
  ushort_t* h2 = ebf;   // ebf dead after layer-0 pull
  ushort_t* q  = t;     // t dead after layer-1 pull
  int* rank = (int*)t;  // t-space unused until gemm1; rank dead after fill_k
  (void)n_in; (void)out_size; (void)ws_size;

  // --- CSR build: rank pass (atomic, leaves degrees) -> scan -> atomic-free fill ---
  hipMemsetAsync(degcnt, 0, (size_t)M * 4, stream);
  dim3 egrid((E + 2047) / 2048, R);
  rank_k<<<egrid, 256, 0, stream>>>(dst, E, N, degcnt, rank);
  int nblkScan = (M + 1023) / 1024;     // 196 <= 1024
  scanA_k<<<nblkScan, 1024, 0, stream>>>(degcnt, M, rowptr, blocksum);
  scanB_k<<<1, 1024, 0, stream>>>(blocksum, nblkScan);
  scanC_k<<<nblkScan, 1024, 0, stream>>>(degcnt, M, blocksum, rowptr, invdeg);
  fill_k<<<egrid, 256, 0, stream>>>(src, dst, rank, rowptr, E, N, eidx);

  // --- prep: embed->bf16, weights -> [outcol][k] bf16 ---
  long n4 = (long)N * D / 4;
  f2bf_vec_k<<<(int)((n4 + 255) / 256), 256, 0, stream>>>(embed, ebf, n4);
  wtrans_k<<<(N1 * D + 255) / 256, 256, 0, stream>>>(w1, w1t, D, D, N1 * D);
  wtrans_k<<<(N2 * D + 255) / 256, 256, 0, stream>>>(w_out, wot, D, C, N2 * D);

  const int pullBlocks2 = ((N + 1) / 2 * 64 + 255) / 256;  // 2 nodes per wave
  const int pullBlocks1 = (N * 64 + 255) / 256;            // 1 node per wave

  // --- layer 0: h = relu(b0 + sum_r agg_r(embed)) ---
  pull_gather256_k<<<pullBlocks2, 256, 0, stream>>>(ebf, D, 0, eidx, rowptr, invdeg,
                                                    R, N, h, b0);

  // --- layer 1: t = h @ w1cat; h2 = relu(b1 + sum_r agg_r(t[:,r*256:])) ---
  {
    dim3 grid(N1 / 128, (N + 127) / 128);
    gemm_mfma_k<4><<<grid, 256, 0, stream>>>(h, w1t, t, N, D, N1);
  }
  pull_gather256_k<<<pullBlocks2, 256, 0, stream>>>(t, N1, D, eidx, rowptr, invdeg,
                                                    R, N, h2, b1);

  // --- layer 2: q = h2 @ wocat; out = b_out + sum_r agg_r(q[:,r*64:]) ---
  {
    dim3 grid(N2 / 128, (N + 127) / 128);
    gemm_mfma_k<4><<<grid, 256, 0, stream>>>(h2, wot, q, N, D, N2);
  }
  pull_out64_k<<<pullBlocks1, 256, 0, stream>>>(q, N2, eidx, rowptr, invdeg,
                                                R, N, out, b_out);
}